// Round 3
// baseline (362.255 us; speedup 1.0000x reference)
//
#include <hip/hip_runtime.h>

// ---------------------------------------------------------------------------
// MultiHeadAttention: B=2, S=2048, E=1024, H=16, D=64, causal. fp32 I/O.
// R14 = R13 (balanced split-K, QBLK=128) with the workspace overflow fixed.
//   R13 footprint was 48MB + 18.6MB partials ~= 66.6MB and the container
//   died with a memory fault; every passing version stayed <= 56.7MB.
//   - Chunk 0 of each multi-chunk qt2 now writes RAW bf16 O straight into
//     its final Out rows + l into a small Laux array (no slot). Slots only
//     for chunks ci>=1: 24/bh (12.4MB).
//   - Slots + Laux OVERLAY the x_bf/wqkvT region (14MB, dead after
//     qkv_gemm; kernels are stream-sequential). Total footprint: 48MB.
//   - attn_combine reads Out-raw + Laux as partial 0, slots for the rest,
//     normalizes, overwrites Out (each thread owns its elements).
// Chunk schedule unchanged: 1280 blocks = 5/CU co-resident (LDS 5x32KB),
// XCD gets 4 heads, per-CU chunk sums = 34 tiles under round-robin.
// GEMMs / prep unchanged.
// ---------------------------------------------------------------------------

typedef __attribute__((ext_vector_type(8))) short short8;
typedef __attribute__((ext_vector_type(4))) short short4v;
typedef __attribute__((ext_vector_type(4))) float floatx4;

#define NB 2
#define SEQ 2048
#define EMB 1024
#define NH 16
#define HD 64
#define M_ROWS (NB * SEQ)        // 4096
#define N_QKV (3 * EMB)          // 3072
#define SLOT_B 16896             // 128x64 bf16 O (16384) + 128 fp32 l (512)
#define SLOTS_PER_BH 24          // chunks ci>=1 only

#define GLL(g, l) __builtin_amdgcn_global_load_lds( \
    (const __attribute__((address_space(1))) void*)(g), \
    (__attribute__((address_space(3))) void*)(l), 16, 0, 0)

#if defined(__HIP_DEVICE_COMPILE__)
#define MFMA16K16(A, B, C) __builtin_amdgcn_mfma_f32_16x16x16bf16_1k(A, B, C, 0, 0, 0)
#else
#define MFMA16K16(A, B, C) (C)   // host pass parses but never executes this
#endif

static __device__ __forceinline__ unsigned short f2bf(float f) {
    union { float f; unsigned int u; } v; v.f = f;
    unsigned int r = v.u + 0x7FFFu + ((v.u >> 16) & 1u);
    return (unsigned short)(r >> 16);
}
static __device__ __forceinline__ float bf2f(unsigned short h) {
    union { unsigned int u; float f; } v; v.u = ((unsigned int)h) << 16;
    return v.f;
}

// packed f32x2 -> bf16x2 (RNE) in one HW instruction
static __device__ __forceinline__ unsigned int cvt_pk_bf16(float lo, float hi) {
#if defined(__HIP_DEVICE_COMPILE__)
    unsigned int r;
    asm("v_cvt_pk_bf16_f32 %0, %1, %2" : "=v"(r) : "v"(lo), "v"(hi));
    return r;
#else
    (void)lo; (void)hi; return 0u;  // host pass never executes
#endif
}
static __device__ __forceinline__ short4v pack4bf(float a, float b, float c, float d) {
    union { unsigned int u[2]; short4v s; } pu;
    pu.u[0] = cvt_pk_bf16(a, b);
    pu.u[1] = cvt_pk_bf16(c, d);
    return pu.s;
}

// Chunk schedule: qq = fid/32 indexes these. Constructed so that under
// round-robin dispatch (XCD = fid%8, CU = (fid/8)%32, slot = fid/256) every
// CU's 5 chunks sum to exactly 34 tiles. FQT = qt2, FCI = chunk index.
// Every (qt2, ci) pair with ci < nc(qt2)=1+(qt2>>2) appears exactly once.
__constant__ unsigned char FQT[40] = {
    3,11,14,15,15, 9,12,13,  7,11,14,15, 6, 9,12,13,
    7,11,15, 5, 6,10,13,14, 10, 2, 4, 5, 8,10,13,14,
    0, 1, 4, 8, 8, 9,12,12 };
__constant__ unsigned char FCI[40] = {
    0, 0, 1, 1, 3, 1, 1, 2,  0, 1, 3, 2, 0, 2, 3, 3,
    1, 2, 0, 0, 1, 0, 0, 0,  2, 0, 0, 1, 1, 1, 1, 2,
    0, 0, 1, 0, 2, 0, 0, 2 };

// slot offset within a bh for (qt2, ci>=1): 24 slots total
static __device__ __forceinline__ int slot_off(int qt2, int ci) {
    int so = (qt2 < 8) ? (qt2 - 4)
           : (qt2 < 12 ? 4 + (qt2 - 8) * 2 : 12 + (qt2 - 12) * 3);
    return so + (ci - 1);
}

// Fused prep: z=0 transpose W_qkv, z=1 transpose W_o, z=2 convert x -> bf16.
__global__ void prep(const float* __restrict__ x,
                     const float* __restrict__ Wqkv, const float* __restrict__ Wo,
                     unsigned short* __restrict__ x_bf,
                     unsigned short* __restrict__ wqkvT, unsigned short* __restrict__ woT) {
    __shared__ unsigned short tile[32][33];
    int z = blockIdx.z;
    int tx = threadIdx.x, ty = threadIdx.y;
    if (z == 2) {
        int id = ((int)blockIdx.y * 96 + (int)blockIdx.x) * 256 + ty * 32 + tx;
        const int n4 = M_ROWS * EMB / 4;
        for (int i = id; i < n4; i += 96 * 32 * 256) {
            float4 v = ((const float4*)x)[i];
            unsigned long long p = (unsigned long long)f2bf(v.x)
                | ((unsigned long long)f2bf(v.y) << 16)
                | ((unsigned long long)f2bf(v.z) << 32)
                | ((unsigned long long)f2bf(v.w) << 48);
            ((unsigned long long*)x_bf)[i] = p;
        }
        return;
    }
    int C = z ? EMB : N_QKV;
    if ((int)blockIdx.x * 32 >= C) return;
    const float* in = z ? Wo : Wqkv;
    unsigned short* out = z ? woT : wqkvT;
    const int R = EMB;
    int c0 = blockIdx.x * 32, r0 = blockIdx.y * 32;
    #pragma unroll
    for (int j = 0; j < 4; ++j)
        tile[ty + j * 8][tx] = f2bf(in[(size_t)(r0 + ty + j * 8) * C + c0 + tx]);
    __syncthreads();
    #pragma unroll
    for (int j = 0; j < 4; ++j)
        out[(size_t)(c0 + ty + j * 8) * R + r0 + tx] = tile[tx][ty + j * 8];
}

// ---------------------------------------------------------------------------
// QKV GEMM: single-barrier dbuf GLL K-loop + LDS-roundtrip coalesced epilogue.
// Q,K -> [B,H,S,D]; V -> [B,H,D,S].
// ---------------------------------------------------------------------------
#define CTS 130   // C-tile LDS stride (shorts), pad 2

__global__ __launch_bounds__(256) void qkv_gemm(
    const unsigned short* __restrict__ A,    // x_bf [4096][1024]
    const unsigned short* __restrict__ Bt,   // W_qkv^T [3072][1024] bf16
    const float* __restrict__ bias,          // [3072] fp32
    unsigned short* __restrict__ qb, unsigned short* __restrict__ kb,
    unsigned short* __restrict__ vb)         // vb: [B,H,D,S]
{
    const int K = EMB;
    __shared__ __align__(16) unsigned short smem[128 * CTS];

    int t = threadIdx.x;
    int m0 = blockIdx.y * 128;
    int n0 = blockIdx.x * 128;
    int w = t >> 6, lane = t & 63, quad = lane >> 4, lcol = lane & 15;
    int wr = w >> 1, wc = w & 1;

    floatx4 zero = {0.f, 0.f, 0.f, 0.f};
    floatx4 acc[4][4];
    #pragma unroll
    for (int i = 0; i < 4; ++i)
        #pragma unroll
        for (int j = 0; j < 4; ++j) acc[i][j] = zero;

    const unsigned short* a0 = A  + (size_t)(m0 + (t >> 2)) * K + ((t & 3) << 3);
    const unsigned short* b0 = Bt + (size_t)(n0 + (t >> 2)) * K + ((t & 3) << 3);
    unsigned short* la = &smem[t << 3];          // + buf*8192 ; Bs at +4096

    GLL(a0, la);
    GLL(a0 + 64 * K, la + 2048);
    GLL(b0, la + 4096);
    GLL(b0 + 64 * K, la + 6144);

    for (int k0 = 0; k0 < K; k0 += 32) {
        int cur = (k0 >> 5) & 1, nxt = cur ^ 1;
        __syncthreads();                         // drains cur's staging loads
        if (k0 + 32 < K) {                       // prefetch nxt AFTER barrier
            GLL(a0 + k0 + 32, la + nxt * 8192);
            GLL(a0 + 64 * K + k0 + 32, la + nxt * 8192 + 2048);
            GLL(b0 + k0 + 32, la + nxt * 8192 + 4096);
            GLL(b0 + 64 * K + k0 + 32, la + nxt * 8192 + 6144);
        }
        const unsigned short* As = &smem[cur * 8192];
        const unsigned short* Bs = As + 4096;
        short8 af[4], bfm[4];
        #pragma unroll
        for (int i = 0; i < 4; ++i)
            af[i] = *(const short8*)(&As[(wr * 64 + i * 16 + lcol) * 32 + quad * 8]);
        #pragma unroll
        for (int j = 0; j < 4; ++j)
            bfm[j] = *(const short8*)(&Bs[(wc * 64 + j * 16 + lcol) * 32 + quad * 8]);
        #pragma unroll
        for (int i = 0; i < 4; ++i)
            #pragma unroll
            for (int j = 0; j < 4; ++j)
                acc[i][j] = __builtin_amdgcn_mfma_f32_16x16x32_bf16(af[i], bfm[j], acc[i][j], 0, 0, 0);
    }

    // ---- epilogue: bias + bf16 into LDS C-tile, then coalesced streams ----
    bool isV = (n0 >= 2 * EMB);
    __syncthreads();
    #pragma unroll
    for (int i = 0; i < 4; ++i) {
        int row0 = wr * 64 + i * 16 + quad * 4;
        #pragma unroll
        for (int j = 0; j < 4; ++j) {
            int col = wc * 64 + j * 16 + lcol;
            float bv = bias[n0 + col];
            #pragma unroll
            for (int r = 0; r < 4; ++r) {
                unsigned short hv = f2bf(acc[i][j][r] + bv);
                if (isV) smem[col * CTS + row0 + r] = hv;   // [feature][token]
                else     smem[(row0 + r) * CTS + col] = hv; // [token][feature]
            }
        }
    }
    __syncthreads();

    int b = m0 >> 11, s0 = m0 & 2047;
    int hbase = (n0 & 1023) >> 6;
    if (!isV) {
        unsigned short* dst = (n0 >= EMB) ? kb : qb;
        #pragma unroll
        for (int it = 0; it < 8; ++it) {
            int job = it * 32 + (t >> 3);
            int tok = job & 127, hh = job >> 7;
            int chunk = t & 7;
            short8 vv = *(const short8*)(&smem[tok * CTS + hh * 64 + chunk * 8]);
            size_t g = ((size_t)((b * NH + hbase + hh) * SEQ + s0 + tok)) * HD + chunk * 8;
            *(short8*)(&dst[g]) = vv;
        }
    } else {
        #pragma unroll
        for (int it = 0; it < 8; ++it) {
            int job = it * 32 + (t >> 3);
            int f = job & 127, half = job >> 7;
            int chunk = (t & 7) + half * 8;
            short8 vv = *(const short8*)(&smem[f * CTS + chunk * 8]);
            int h = hbase + (f >> 6), d = f & 63;
            size_t g = ((size_t)((b * NH + h) * HD + d)) * SEQ + s0 + chunk * 8;
            *(short8*)(&vb[g]) = vv;
        }
    }
}

// ---------------------------------------------------------------------------
// Causal flash attention, QBLK=128, balanced split-K chunks of <=8 tiles.
// Block: 256 threads (4 waves). Wave w owns query groups gb = q0+64g+16w.
// Per 64-key tile: S^T = K*Q^T, P^T packed bf16 via cvt_pk (direct 16x16x16
// B-frag), O^T += V^T*P^T (V frags read once, both groups), l via ones-MFMA.
// nc==1: final write. nc>1, ci==0: raw bf16 O -> Out rows + l -> Laux.
// nc>1, ci>=1: partial slot (bf16 O + f32 l).
// ---------------------------------------------------------------------------
__global__ __launch_bounds__(256, 5) void attn_fused(
    const unsigned short* __restrict__ Q,   // [B*H][S][D]
    const unsigned short* __restrict__ Kk,  // [B*H][S][D]
    const unsigned short* __restrict__ Vt,  // [B*H][D][S]
    unsigned short* __restrict__ Out,       // [b][s][h*64+d]
    unsigned char* __restrict__ Part,       // 24 slots per bh (ci>=1)
    float* __restrict__ Laux)               // [bh][qt2-4][128] chunk-0 l
{
    __shared__ __align__(16) unsigned short Ks[2][64 * 64];
    __shared__ __align__(16) unsigned short Vs[2][64 * 64];

    // ---- dispatch map ----
    int fid = (int)blockIdx.y * 40 + (int)blockIdx.x;   // 0..1279, dispatch order
    int bh  = (fid & 7) * 4 + ((fid >> 3) & 3);         // XCD fid%8 -> 4 heads
    int qq  = fid >> 5;                                 // 0..39 chunk slot
    int qt2 = FQT[qq];
    int ci  = FCI[qq];
    int nc  = 1 + (qt2 >> 2);                           // chunks for this qt2
    int nt  = 2 * (qt2 + 1);                            // total 64-key tiles
    int t0  = (nt * ci) / nc, t1 = (nt * (ci + 1)) / nc;
    int q0  = qt2 * 128;

    int t = threadIdx.x;
    int w = t >> 6, lane = t & 63, quad = lane >> 4, lcol = lane & 15;
    const size_t hoff = (size_t)bh * SEQ * HD;
    const float SC = 0.18033688011112043f;   // (1/sqrt(64)) * log2(e)

    // Q strips (B-operand), two groups per wave
    short8 aq[2][2];
    #pragma unroll
    for (int g = 0; g < 2; ++g) {
        const unsigned short* qp = Q + hoff
            + (size_t)(q0 + g * 64 + 16 * w + lcol) * HD + quad * 8;
        aq[g][0] = *(const short8*)qp;
        aq[g][1] = *(const short8*)(qp + 32);
    }

    int srow = t >> 3;                       // 0..31
    int ss   = (t & 7) ^ (srow & 7);         // pre-swizzled global source
    const unsigned short* kgl = Kk + hoff + (size_t)srow * HD + ss * 8;
    const unsigned short* vgl = Vt + hoff + (size_t)srow * SEQ + ss * 8;
    unsigned short* kld = &Ks[0][t * 8];
    unsigned short* vld = &Vs[0][t * 8];

    floatx4 zero = {0.f, 0.f, 0.f, 0.f};
    floatx4 O[2][4];                 // O^T: row=d(quad*4+r in td*16), col=query lcol
    floatx4 lacc[2];                 // all rows = l[query lcol]
    #pragma unroll
    for (int g = 0; g < 2; ++g) {
        lacc[g] = zero;
        #pragma unroll
        for (int td = 0; td < 4; ++td) O[g][td] = zero;
    }

    short4v ones4;
    #pragma unroll
    for (int jj = 0; jj < 4; ++jj) ones4[jj] = (short)0x3F80;  // bf16 1.0

    {   // prologue: stage tile t0 into buf (t0&1)
        int pb = (t0 & 1) * 4096;
        size_t k0 = (size_t)t0 * 64;
        GLL(kgl + k0 * HD, kld + pb);
        GLL(kgl + (k0 + 32) * HD, kld + pb + 2048);
        GLL(vgl + k0, vld + pb);
        GLL(vgl + (size_t)32 * SEQ + k0, vld + pb + 2048);
    }

    int sx0 = (quad ^ (lcol & 7)) << 3;
    int sx1 = sx0 ^ 32;

    for (int kt = t0; kt < t1; ++kt) {
        int cur = kt & 1, nxt = cur ^ 1;
        __syncthreads();                     // drains tile-kt staging loads
        if (kt + 1 < t1) {
            size_t k0 = (size_t)(kt + 1) * 64;
            GLL(kgl + k0 * HD, kld + nxt * 4096);
            GLL(kgl + (k0 + 32) * HD, kld + nxt * 4096 + 2048);
            GLL(vgl + k0, vld + nxt * 4096);
            GLL(vgl + (size_t)32 * SEQ + k0, vld + nxt * 4096 + 2048);
        }

        const unsigned short* ksr = &Ks[cur][0];
        const unsigned short* vsr = &Vs[cur][0];
        short8 bk0[4], bk1[4];
        #pragma unroll
        for (int tc = 0; tc < 4; ++tc) {
            int rb = (tc * 16 + lcol) << 6;
            bk0[tc] = *(const short8*)(ksr + rb + sx0);
            bk1[tc] = *(const short8*)(ksr + rb + sx1);
        }

        short4v pk[2][4];
        bool act[2];
        #pragma unroll
        for (int g = 0; g < 2; ++g) {
            const int gb = q0 + g * 64 + 16 * w;     // wave-uniform
            act[g] = (kt * 64 <= gb + 15);
            if (act[g]) {
                // S^T = K * Q^T  (A = K tile rows=keys, B = Q strip cols=queries)
                floatx4 sacc[4];
                #pragma unroll
                for (int tc = 0; tc < 4; ++tc) {
                    sacc[tc] = __builtin_amdgcn_mfma_f32_16x16x32_bf16(bk0[tc], aq[g][0], zero, 0, 0, 0);
                    sacc[tc] = __builtin_amdgcn_mfma_f32_16x16x32_bf16(bk1[tc], aq[g][1], sacc[tc], 0, 0, 0);
                }
                if (kt * 64 + 63 > gb) {             // diagonal tile: mask
                    int qrow = gb + lcol;
                    #pragma unroll
                    for (int tc = 0; tc < 4; ++tc) {
                        float p[4];
                        #pragma unroll
                        for (int r = 0; r < 4; ++r) {
                            float e = __builtin_amdgcn_exp2f(sacc[tc][r] * SC);
                            p[r] = (kt * 64 + tc * 16 + quad * 4 + r > qrow) ? 0.f : e;
                        }
                        pk[g][tc] = pack4bf(p[0], p[1], p[2], p[3]);
                    }
                } else {
                    #pragma unroll
                    for (int tc = 0; tc < 4; ++tc) {
                        pk[g][tc] = pack4bf(
                            __builtin_amdgcn_exp2f(sacc[tc][0] * SC),
                            __builtin_amdgcn_exp2f(sacc[tc][1] * SC),
                            __builtin_amdgcn_exp2f(sacc[tc][2] * SC),
                            __builtin_amdgcn_exp2f(sacc[tc][3] * SC));
                    }
                }
            }
        }

        // O^T += V^T * P^T  -- V frags read ONCE, consumed by both groups
        #pragma unroll
        for (int td = 0; td < 4; ++td) {
            short4v va[4];
            #pragma unroll
            for (int tc = 0; tc < 4; ++tc) {
                int seg = ((tc << 1) + (quad >> 1)) ^ (lcol & 7);
                va[tc] = *(const short4v*)(vsr + ((td * 16 + lcol) << 6) + (seg << 3) + ((quad & 1) << 2));
            }
            if (act[0]) {
                #pragma unroll
                for (int tc = 0; tc < 4; ++tc)
                    O[0][td] = MFMA16K16(va[tc], pk[0][tc], O[0][td]);
            }
            if (act[1]) {
                #pragma unroll
                for (int tc = 0; tc < 4; ++tc)
                    O[1][td] = MFMA16K16(va[tc], pk[1][tc], O[1][td]);
            }
        }
        // l[q] += sum_key P^T[key][q]
        #pragma unroll
        for (int g = 0; g < 2; ++g) {
            if (act[g]) {
                #pragma unroll
                for (int tc = 0; tc < 4; ++tc)
                    lacc[g] = MFMA16K16(ones4, pk[g][tc], lacc[g]);
            }
        }
    }

    if (nc == 1) {
        // ---- single chunk: final normalize + write ----
        int b = bh >> 4, h = bh & 15;
        #pragma unroll
        for (int g = 0; g < 2; ++g) {
            int qrow = q0 + g * 64 + 16 * w + lcol;
            float inv = 1.0f / lacc[g][0];
            size_t obase = ((size_t)b * SEQ + qrow) * EMB + (size_t)h * HD + quad * 4;
            #pragma unroll
            for (int td = 0; td < 4; ++td) {
                short4v ov;
                #pragma unroll
                for (int r = 0; r < 4; ++r) ov[r] = (short)f2bf(O[g][td][r] * inv);
                *(short4v*)(&Out[obase + td * 16]) = ov;
            }
        }
    } else if (ci == 0) {
        // ---- chunk 0: RAW bf16 O into final Out rows; l into Laux ----
        int b = bh >> 4, h = bh & 15;
        float* lrow = Laux + ((size_t)bh * 12 + (qt2 - 4)) * 128;
        #pragma unroll
        for (int g = 0; g < 2; ++g) {
            int ql = g * 64 + 16 * w + lcol;
            int qrow = q0 + ql;
            size_t obase = ((size_t)b * SEQ + qrow) * EMB + (size_t)h * HD + quad * 4;
            #pragma unroll
            for (int td = 0; td < 4; ++td) {
                short4v ov;
                #pragma unroll
                for (int r = 0; r < 4; ++r) ov[r] = (short)f2bf(O[g][td][r]);
                *(short4v*)(&Out[obase + td * 16]) = ov;
            }
            if (quad == 0) lrow[ql] = lacc[g][0];
        }
    } else {
        // ---- chunks ci>=1: partial slot (raw bf16 O + f32 l) ----
        unsigned char* sp = Part
            + (size_t)(bh * SLOTS_PER_BH + slot_off(qt2, ci)) * SLOT_B;
        unsigned short* sO = (unsigned short*)sp;       // [q_local 0..127][d 0..63]
        float* sL = (float*)(sp + 16384);
        #pragma unroll
        for (int g = 0; g < 2; ++g) {
            int ql = g * 64 + 16 * w + lcol;
            #pragma unroll
            for (int td = 0; td < 4; ++td) {
                short4v ov;
                #pragma unroll
                for (int r = 0; r < 4; ++r) ov[r] = (short)f2bf(O[g][td][r]);
                *(short4v*)(&sO[ql * 64 + td * 16 + quad * 4]) = ov;
            }
            if (quad == 0) sL[ql] = lacc[g][0];
        }
    }
}

// merge chunk-0 (raw in Out + Laux) with slots 1..nc-1, normalize, rewrite Out
__global__ __launch_bounds__(256) void attn_combine(
    const unsigned char* __restrict__ Part, const float* __restrict__ Laux,
    unsigned short* __restrict__ Out)
{
    int qt2 = 4 + (int)blockIdx.x;           // 4..15
    int bh = blockIdx.y;
    int nc = 1 + (qt2 >> 2);                 // 2..4
    const unsigned char* base = Part
        + (size_t)(bh * SLOTS_PER_BH + slot_off(qt2, 1)) * SLOT_B;
    const float* lrow = Laux + ((size_t)bh * 12 + (qt2 - 4)) * 128;
    int b = bh >> 4, h = bh & 15;
    size_t obase = ((size_t)b * SEQ + qt2 * 128) * EMB + (size_t)h * HD;
    int t = threadIdx.x;
    #pragma unroll
    for (int it = 0; it < 4; ++it) {
        int job = it * 256 + t;              // 0..1023 = 128 rows x 8 col-chunks
        int row = job >> 3, c8 = (job & 7) * 8;
        unsigned short* op = &Out[obase + (size_t)row * EMB + c8];
        float acc8[8];
        short8 v0 = *(const short8*)op;      // chunk-0 raw partial
        #pragma unroll
        for (int e = 0; e < 8; ++e) acc8[e] = bf2f((unsigned short)v0[e]);
        float lsum = lrow[row];
        for (int k = 1; k < nc; ++k) {
            const unsigned char* sp = base + (size_t)(k - 1) * SLOT_B;
            const unsigned short* sO = (const unsigned short*)sp;
            const float* sL = (const float*)(sp + 16384);
            short8 vv = *(const short8*)(&sO[row * 64 + c8]);
            #pragma unroll
            for (int e = 0; e < 8; ++e) acc8[e] += bf2f((unsigned short)vv[e]);
            lsum += sL[row];
        }
        float inv = 1.0f / lsum;
        short8 ov;
        #pragma unroll
        for (int e = 0; e < 8; ++e) ov[e] = (short)f2bf(acc8[e] * inv);
        *(short8*)op = ov;
    }
}

// ---------------------------------------------------------------------------
// Output projection: single-barrier dbuf GLL K-loop. fp32 bias, fp32 out.
// ---------------------------------------------------------------------------
__global__ __launch_bounds__(256) void oproj_gemm(
    const unsigned short* __restrict__ A,    // [4096][1024] bf16
    const unsigned short* __restrict__ Bt,   // W_o^T [1024][1024] bf16
    const float* __restrict__ bias,          // [1024] fp32
    float* __restrict__ Cout)                // [4096][1024] fp32
{
    const int K = EMB;
    __shared__ __align__(16) unsigned short smem[2 * 8192];
    int t = threadIdx.x;
    int m0 = blockIdx.y * 128;
    int n0 = blockIdx.x * 128;
    int w = t >> 6, lane = t & 63, quad = lane >> 4, lcol = lane & 15;
    int wr = w >> 1, wc = w & 1;

    floatx4 zero = {0.f, 0.f, 0.f, 0.f};
    floatx4 acc[4][4];
    #pragma unroll
    for (int i = 0; i < 4; ++i)
        #pragma unroll
        for (int j = 0; j < 4; ++j) acc[i][j] = zero;

    const unsigned short* a0 = A  + (size_t)(m0 + (t >> 2)) * K + ((t & 3) << 3);
    const unsigned short* b0 = Bt + (size_t)(n0 + (t >> 2)) * K + ((t & 3) << 3);
    unsigned short* la = &smem[t << 3];

    GLL(a0, la);
    GLL(a0 + 64 * K, la + 2048);
    GLL(b0, la + 4096);
    GLL(b0 + 64 * K, la + 6144);

    for (int k0 = 0; k0 < K; k0 += 32) {
        int cur = (k0 >> 5) & 1, nxt = cur ^ 1;
        __syncthreads();
        if (k0 + 32 < K) {
            GLL(a0 + k0 + 32, la + nxt * 8192);
            GLL(a0 + 64 * K + k0 + 32, la + nxt * 8192 + 2048);
            GLL(b0 + k0 + 32, la + nxt * 8192 + 4096);
            GLL(b0 + 64 * K + k0 + 32, la + nxt * 8192 + 6144);
        }
        const unsigned short* As = &smem[cur * 8192];
        const unsigned short* Bs = As + 4096;
        short8 af[4], bfm[4];
        #pragma unroll
        for (int i = 0; i < 4; ++i)
            af[i] = *(const short8*)(&As[(wr * 64 + i * 16 + lcol) * 32 + quad * 8]);
        #pragma unroll
        for (int j = 0; j < 4; ++j)
            bfm[j] = *(const short8*)(&Bs[(wc * 64 + j * 16 + lcol) * 32 + quad * 8]);
        #pragma unroll
        for (int i = 0; i < 4; ++i)
            #pragma unroll
            for (int j = 0; j < 4; ++j)
                acc[i][j] = __builtin_amdgcn_mfma_f32_16x16x32_bf16(af[i], bfm[j], acc[i][j], 0, 0, 0);
    }

    #pragma unroll
    for (int i = 0; i < 4; ++i) {
        int m = m0 + wr * 64 + i * 16 + quad * 4;
        #pragma unroll
        for (int j = 0; j < 4; ++j) {
            int n = n0 + wc * 64 + j * 16 + lcol;
            float bv = bias[n];
            #pragma unroll
            for (int r = 0; r < 4; ++r)
                Cout[(size_t)(m + r) * EMB + n] = acc[i][j][r] + bv;
        }
    }
}

// ---------------------------------------------------------------------------
extern "C" void kernel_launch(void* const* d_in, const int* in_sizes, int n_in,
                              void* d_out, int out_size, void* d_ws, size_t ws_size,
                              hipStream_t stream) {
    (void)in_sizes; (void)n_in; (void)out_size; (void)ws_size;
    char* ws = (char*)d_ws;
    const size_t OFF_X     = 0;                                      // 8 MB
    const size_t OFF_WQKVT = OFF_X     + (size_t)M_ROWS * EMB * 2;   // 6 MB
    const size_t OFF_WOT   = OFF_WQKVT + (size_t)N_QKV * EMB * 2;    // 2 MB
    const size_t OFF_Q     = OFF_WOT   + (size_t)EMB * EMB * 2;      // 8 MB
    const size_t OFF_K     = OFF_Q     + (size_t)M_ROWS * EMB * 2;   // 8 MB
    const size_t OFF_V     = OFF_K     + (size_t)M_ROWS * EMB * 2;   // 8 MB
    const size_t OFF_ATTN  = OFF_V     + (size_t)M_ROWS * EMB * 2;   // 8 MB
    // Partials OVERLAY x_bf+wqkvT (dead after qkv_gemm). 12.97MB + 0.19MB
    // fits in the 14MB region; woT at +14MB untouched. Total ws use: 48MB.
    const size_t OFF_PART  = OFF_X;
    const size_t OFF_LAUX  = OFF_PART + (size_t)32 * SLOTS_PER_BH * SLOT_B;

    const float* x    = (const float*)d_in[0];
    const float* Wqkv = (const float*)d_in[1];
    const float* bqkv = (const float*)d_in[2];
    const float* Wo   = (const float*)d_in[3];
    const float* bo   = (const float*)d_in[4];

    unsigned short* x_bf  = (unsigned short*)(ws + OFF_X);
    unsigned short* wqkvT = (unsigned short*)(ws + OFF_WQKVT);
    unsigned short* woT   = (unsigned short*)(ws + OFF_WOT);
    unsigned short* qb    = (unsigned short*)(ws + OFF_Q);
    unsigned short* kb    = (unsigned short*)(ws + OFF_K);
    unsigned short* vb    = (unsigned short*)(ws + OFF_V);    // [B,H,D,S]
    unsigned short* attn  = (unsigned short*)(ws + OFF_ATTN);
    unsigned char*  part  = (unsigned char*)(ws + OFF_PART);
    float*          laux  = (float*)(ws + OFF_LAUX);

    prep<<<dim3(96, 32, 3), dim3(32, 8), 0, stream>>>(x, Wqkv, Wo, x_bf, wqkvT, woT);

    qkv_gemm<<<dim3(N_QKV / 128, M_ROWS / 128), 256, 0, stream>>>(x_bf, wqkvT, bqkv, qb, kb, vb);
    attn_fused<<<dim3(40, NB * NH), 256, 0, stream>>>(qb, kb, vb, attn, part, laux);
    attn_combine<<<dim3(12, NB * NH), 256, 0, stream>>>(part, laux, attn);
    oproj_gemm<<<dim3(EMB / 128, M_ROWS / 128), 256, 0, stream>>>(attn, woT, bo, (float*)d_out);
}

// Round 4
// 201.004 us; speedup vs baseline: 1.8022x; 1.8022x over previous
//
#include <hip/hip_runtime.h>

// ---------------------------------------------------------------------------
// MultiHeadAttention: B=2, S=2048, E=1024, H=16, D=64, causal. fp32 I/O.
// R15 = R14 with the register-spill fixed: __launch_bounds__(256,5) forced a
//   ~102-VGPR cap -> compiler spilled the hot-loop state (VGPR 84->48,
//   WRITE_SIZE 8MB->464MB of scratch, MfmaUtil 5.8%, 208us). Reverted to
//   plain __launch_bounds__(256) (= R12 codegen: 84 VGPR, zero spill).
//   Occupancy is then LDS-limited at 5 blocks/CU (5 x 32KB = 160KB), which
//   is exactly what the chunk schedule wants -- now without spilling.
// Everything else unchanged from R14 (passed, absmax 0.0039):
//   - Balanced split-K: 1280 blocks, chunks of <=8 tiles, per-CU sums = 34
//     tiles under round-robin; XCD gets 4 heads (L2 locality).
//   - Chunk 0 of multi-chunk qt2 writes RAW bf16 O into final Out rows + l
//     into Laux; chunks ci>=1 use partial slots; combine normalizes.
//   - Partials overlay x_bf/wqkvT (dead after qkv_gemm). Footprint 48MB.
// GEMMs / prep unchanged.
// ---------------------------------------------------------------------------

typedef __attribute__((ext_vector_type(8))) short short8;
typedef __attribute__((ext_vector_type(4))) short short4v;
typedef __attribute__((ext_vector_type(4))) float floatx4;

#define NB 2
#define SEQ 2048
#define EMB 1024
#define NH 16
#define HD 64
#define M_ROWS (NB * SEQ)        // 4096
#define N_QKV (3 * EMB)          // 3072
#define SLOT_B 16896             // 128x64 bf16 O (16384) + 128 fp32 l (512)
#define SLOTS_PER_BH 24          // chunks ci>=1 only

#define GLL(g, l) __builtin_amdgcn_global_load_lds( \
    (const __attribute__((address_space(1))) void*)(g), \
    (__attribute__((address_space(3))) void*)(l), 16, 0, 0)

#if defined(__HIP_DEVICE_COMPILE__)
#define MFMA16K16(A, B, C) __builtin_amdgcn_mfma_f32_16x16x16bf16_1k(A, B, C, 0, 0, 0)
#else
#define MFMA16K16(A, B, C) (C)   // host pass parses but never executes this
#endif

static __device__ __forceinline__ unsigned short f2bf(float f) {
    union { float f; unsigned int u; } v; v.f = f;
    unsigned int r = v.u + 0x7FFFu + ((v.u >> 16) & 1u);
    return (unsigned short)(r >> 16);
}
static __device__ __forceinline__ float bf2f(unsigned short h) {
    union { unsigned int u; float f; } v; v.u = ((unsigned int)h) << 16;
    return v.f;
}

// packed f32x2 -> bf16x2 (RNE) in one HW instruction
static __device__ __forceinline__ unsigned int cvt_pk_bf16(float lo, float hi) {
#if defined(__HIP_DEVICE_COMPILE__)
    unsigned int r;
    asm("v_cvt_pk_bf16_f32 %0, %1, %2" : "=v"(r) : "v"(lo), "v"(hi));
    return r;
#else
    (void)lo; (void)hi; return 0u;  // host pass never executes
#endif
}
static __device__ __forceinline__ short4v pack4bf(float a, float b, float c, float d) {
    union { unsigned int u[2]; short4v s; } pu;
    pu.u[0] = cvt_pk_bf16(a, b);
    pu.u[1] = cvt_pk_bf16(c, d);
    return pu.s;
}

// Chunk schedule: qq = fid/32 indexes these. Constructed so that under
// round-robin dispatch (XCD = fid%8, CU = (fid/8)%32, slot = fid/256) every
// CU's 5 chunks sum to exactly 34 tiles. FQT = qt2, FCI = chunk index.
// Every (qt2, ci) pair with ci < nc(qt2)=1+(qt2>>2) appears exactly once.
__constant__ unsigned char FQT[40] = {
    3,11,14,15,15, 9,12,13,  7,11,14,15, 6, 9,12,13,
    7,11,15, 5, 6,10,13,14, 10, 2, 4, 5, 8,10,13,14,
    0, 1, 4, 8, 8, 9,12,12 };
__constant__ unsigned char FCI[40] = {
    0, 0, 1, 1, 3, 1, 1, 2,  0, 1, 3, 2, 0, 2, 3, 3,
    1, 2, 0, 0, 1, 0, 0, 0,  2, 0, 0, 1, 1, 1, 1, 2,
    0, 0, 1, 0, 2, 0, 0, 2 };

// slot offset within a bh for (qt2, ci>=1): 24 slots total
static __device__ __forceinline__ int slot_off(int qt2, int ci) {
    int so = (qt2 < 8) ? (qt2 - 4)
           : (qt2 < 12 ? 4 + (qt2 - 8) * 2 : 12 + (qt2 - 12) * 3);
    return so + (ci - 1);
}

// Fused prep: z=0 transpose W_qkv, z=1 transpose W_o, z=2 convert x -> bf16.
__global__ void prep(const float* __restrict__ x,
                     const float* __restrict__ Wqkv, const float* __restrict__ Wo,
                     unsigned short* __restrict__ x_bf,
                     unsigned short* __restrict__ wqkvT, unsigned short* __restrict__ woT) {
    __shared__ unsigned short tile[32][33];
    int z = blockIdx.z;
    int tx = threadIdx.x, ty = threadIdx.y;
    if (z == 2) {
        int id = ((int)blockIdx.y * 96 + (int)blockIdx.x) * 256 + ty * 32 + tx;
        const int n4 = M_ROWS * EMB / 4;
        for (int i = id; i < n4; i += 96 * 32 * 256) {
            float4 v = ((const float4*)x)[i];
            unsigned long long p = (unsigned long long)f2bf(v.x)
                | ((unsigned long long)f2bf(v.y) << 16)
                | ((unsigned long long)f2bf(v.z) << 32)
                | ((unsigned long long)f2bf(v.w) << 48);
            ((unsigned long long*)x_bf)[i] = p;
        }
        return;
    }
    int C = z ? EMB : N_QKV;
    if ((int)blockIdx.x * 32 >= C) return;
    const float* in = z ? Wo : Wqkv;
    unsigned short* out = z ? woT : wqkvT;
    const int R = EMB;
    int c0 = blockIdx.x * 32, r0 = blockIdx.y * 32;
    #pragma unroll
    for (int j = 0; j < 4; ++j)
        tile[ty + j * 8][tx] = f2bf(in[(size_t)(r0 + ty + j * 8) * C + c0 + tx]);
    __syncthreads();
    #pragma unroll
    for (int j = 0; j < 4; ++j)
        out[(size_t)(c0 + ty + j * 8) * R + r0 + tx] = tile[tx][ty + j * 8];
}

// ---------------------------------------------------------------------------
// QKV GEMM: single-barrier dbuf GLL K-loop + LDS-roundtrip coalesced epilogue.
// Q,K -> [B,H,S,D]; V -> [B,H,D,S].
// ---------------------------------------------------------------------------
#define CTS 130   // C-tile LDS stride (shorts), pad 2

__global__ __launch_bounds__(256) void qkv_gemm(
    const unsigned short* __restrict__ A,    // x_bf [4096][1024]
    const unsigned short* __restrict__ Bt,   // W_qkv^T [3072][1024] bf16
    const float* __restrict__ bias,          // [3072] fp32
    unsigned short* __restrict__ qb, unsigned short* __restrict__ kb,
    unsigned short* __restrict__ vb)         // vb: [B,H,D,S]
{
    const int K = EMB;
    __shared__ __align__(16) unsigned short smem[128 * CTS];

    int t = threadIdx.x;
    int m0 = blockIdx.y * 128;
    int n0 = blockIdx.x * 128;
    int w = t >> 6, lane = t & 63, quad = lane >> 4, lcol = lane & 15;
    int wr = w >> 1, wc = w & 1;

    floatx4 zero = {0.f, 0.f, 0.f, 0.f};
    floatx4 acc[4][4];
    #pragma unroll
    for (int i = 0; i < 4; ++i)
        #pragma unroll
        for (int j = 0; j < 4; ++j) acc[i][j] = zero;

    const unsigned short* a0 = A  + (size_t)(m0 + (t >> 2)) * K + ((t & 3) << 3);
    const unsigned short* b0 = Bt + (size_t)(n0 + (t >> 2)) * K + ((t & 3) << 3);
    unsigned short* la = &smem[t << 3];          // + buf*8192 ; Bs at +4096

    GLL(a0, la);
    GLL(a0 + 64 * K, la + 2048);
    GLL(b0, la + 4096);
    GLL(b0 + 64 * K, la + 6144);

    for (int k0 = 0; k0 < K; k0 += 32) {
        int cur = (k0 >> 5) & 1, nxt = cur ^ 1;
        __syncthreads();                         // drains cur's staging loads
        if (k0 + 32 < K) {                       // prefetch nxt AFTER barrier
            GLL(a0 + k0 + 32, la + nxt * 8192);
            GLL(a0 + 64 * K + k0 + 32, la + nxt * 8192 + 2048);
            GLL(b0 + k0 + 32, la + nxt * 8192 + 4096);
            GLL(b0 + 64 * K + k0 + 32, la + nxt * 8192 + 6144);
        }
        const unsigned short* As = &smem[cur * 8192];
        const unsigned short* Bs = As + 4096;
        short8 af[4], bfm[4];
        #pragma unroll
        for (int i = 0; i < 4; ++i)
            af[i] = *(const short8*)(&As[(wr * 64 + i * 16 + lcol) * 32 + quad * 8]);
        #pragma unroll
        for (int j = 0; j < 4; ++j)
            bfm[j] = *(const short8*)(&Bs[(wc * 64 + j * 16 + lcol) * 32 + quad * 8]);
        #pragma unroll
        for (int i = 0; i < 4; ++i)
            #pragma unroll
            for (int j = 0; j < 4; ++j)
                acc[i][j] = __builtin_amdgcn_mfma_f32_16x16x32_bf16(af[i], bfm[j], acc[i][j], 0, 0, 0);
    }

    // ---- epilogue: bias + bf16 into LDS C-tile, then coalesced streams ----
    bool isV = (n0 >= 2 * EMB);
    __syncthreads();
    #pragma unroll
    for (int i = 0; i < 4; ++i) {
        int row0 = wr * 64 + i * 16 + quad * 4;
        #pragma unroll
        for (int j = 0; j < 4; ++j) {
            int col = wc * 64 + j * 16 + lcol;
            float bv = bias[n0 + col];
            #pragma unroll
            for (int r = 0; r < 4; ++r) {
                unsigned short hv = f2bf(acc[i][j][r] + bv);
                if (isV) smem[col * CTS + row0 + r] = hv;   // [feature][token]
                else     smem[(row0 + r) * CTS + col] = hv; // [token][feature]
            }
        }
    }
    __syncthreads();

    int b = m0 >> 11, s0 = m0 & 2047;
    int hbase = (n0 & 1023) >> 6;
    if (!isV) {
        unsigned short* dst = (n0 >= EMB) ? kb : qb;
        #pragma unroll
        for (int it = 0; it < 8; ++it) {
            int job = it * 32 + (t >> 3);
            int tok = job & 127, hh = job >> 7;
            int chunk = t & 7;
            short8 vv = *(const short8*)(&smem[tok * CTS + hh * 64 + chunk * 8]);
            size_t g = ((size_t)((b * NH + hbase + hh) * SEQ + s0 + tok)) * HD + chunk * 8;
            *(short8*)(&dst[g]) = vv;
        }
    } else {
        #pragma unroll
        for (int it = 0; it < 8; ++it) {
            int job = it * 32 + (t >> 3);
            int f = job & 127, half = job >> 7;
            int chunk = (t & 7) + half * 8;
            short8 vv = *(const short8*)(&smem[f * CTS + chunk * 8]);
            int h = hbase + (f >> 6), d = f & 63;
            size_t g = ((size_t)((b * NH + h) * HD + d)) * SEQ + s0 + chunk * 8;
            *(short8*)(&vb[g]) = vv;
        }
    }
}

// ---------------------------------------------------------------------------
// Causal flash attention, QBLK=128, balanced split-K chunks of <=8 tiles.
// Block: 256 threads (4 waves). Wave w owns query groups gb = q0+64g+16w.
// Per 64-key tile: S^T = K*Q^T, P^T packed bf16 via cvt_pk (direct 16x16x16
// B-frag), O^T += V^T*P^T (V frags read once, both groups), l via ones-MFMA.
// nc==1: final write. nc>1, ci==0: raw bf16 O -> Out rows + l -> Laux.
// nc>1, ci>=1: partial slot (bf16 O + f32 l).
// NOTE: plain launch_bounds(256). (256,5) forced a ~102-VGPR cap -> spill
// (VGPR 48, 464MB scratch writes, 208us). 84 VGPR no-spill > occupancy hint.
// ---------------------------------------------------------------------------
__global__ __launch_bounds__(256) void attn_fused(
    const unsigned short* __restrict__ Q,   // [B*H][S][D]
    const unsigned short* __restrict__ Kk,  // [B*H][S][D]
    const unsigned short* __restrict__ Vt,  // [B*H][D][S]
    unsigned short* __restrict__ Out,       // [b][s][h*64+d]
    unsigned char* __restrict__ Part,       // 24 slots per bh (ci>=1)
    float* __restrict__ Laux)               // [bh][qt2-4][128] chunk-0 l
{
    __shared__ __align__(16) unsigned short Ks[2][64 * 64];
    __shared__ __align__(16) unsigned short Vs[2][64 * 64];

    // ---- dispatch map ----
    int fid = (int)blockIdx.y * 40 + (int)blockIdx.x;   // 0..1279, dispatch order
    int bh  = (fid & 7) * 4 + ((fid >> 3) & 3);         // XCD fid%8 -> 4 heads
    int qq  = fid >> 5;                                 // 0..39 chunk slot
    int qt2 = FQT[qq];
    int ci  = FCI[qq];
    int nc  = 1 + (qt2 >> 2);                           // chunks for this qt2
    int nt  = 2 * (qt2 + 1);                            // total 64-key tiles
    int t0  = (nt * ci) / nc, t1 = (nt * (ci + 1)) / nc;
    int q0  = qt2 * 128;

    int t = threadIdx.x;
    int w = t >> 6, lane = t & 63, quad = lane >> 4, lcol = lane & 15;
    const size_t hoff = (size_t)bh * SEQ * HD;
    const float SC = 0.18033688011112043f;   // (1/sqrt(64)) * log2(e)

    // Q strips (B-operand), two groups per wave
    short8 aq[2][2];
    #pragma unroll
    for (int g = 0; g < 2; ++g) {
        const unsigned short* qp = Q + hoff
            + (size_t)(q0 + g * 64 + 16 * w + lcol) * HD + quad * 8;
        aq[g][0] = *(const short8*)qp;
        aq[g][1] = *(const short8*)(qp + 32);
    }

    int srow = t >> 3;                       // 0..31
    int ss   = (t & 7) ^ (srow & 7);         // pre-swizzled global source
    const unsigned short* kgl = Kk + hoff + (size_t)srow * HD + ss * 8;
    const unsigned short* vgl = Vt + hoff + (size_t)srow * SEQ + ss * 8;
    unsigned short* kld = &Ks[0][t * 8];
    unsigned short* vld = &Vs[0][t * 8];

    floatx4 zero = {0.f, 0.f, 0.f, 0.f};
    floatx4 O[2][4];                 // O^T: row=d(quad*4+r in td*16), col=query lcol
    floatx4 lacc[2];                 // all rows = l[query lcol]
    #pragma unroll
    for (int g = 0; g < 2; ++g) {
        lacc[g] = zero;
        #pragma unroll
        for (int td = 0; td < 4; ++td) O[g][td] = zero;
    }

    short4v ones4;
    #pragma unroll
    for (int jj = 0; jj < 4; ++jj) ones4[jj] = (short)0x3F80;  // bf16 1.0

    {   // prologue: stage tile t0 into buf (t0&1)
        int pb = (t0 & 1) * 4096;
        size_t k0 = (size_t)t0 * 64;
        GLL(kgl + k0 * HD, kld + pb);
        GLL(kgl + (k0 + 32) * HD, kld + pb + 2048);
        GLL(vgl + k0, vld + pb);
        GLL(vgl + (size_t)32 * SEQ + k0, vld + pb + 2048);
    }

    int sx0 = (quad ^ (lcol & 7)) << 3;
    int sx1 = sx0 ^ 32;

    for (int kt = t0; kt < t1; ++kt) {
        int cur = kt & 1, nxt = cur ^ 1;
        __syncthreads();                     // drains tile-kt staging loads
        if (kt + 1 < t1) {
            size_t k0 = (size_t)(kt + 1) * 64;
            GLL(kgl + k0 * HD, kld + nxt * 4096);
            GLL(kgl + (k0 + 32) * HD, kld + nxt * 4096 + 2048);
            GLL(vgl + k0, vld + nxt * 4096);
            GLL(vgl + (size_t)32 * SEQ + k0, vld + nxt * 4096 + 2048);
        }

        const unsigned short* ksr = &Ks[cur][0];
        const unsigned short* vsr = &Vs[cur][0];
        short8 bk0[4], bk1[4];
        #pragma unroll
        for (int tc = 0; tc < 4; ++tc) {
            int rb = (tc * 16 + lcol) << 6;
            bk0[tc] = *(const short8*)(ksr + rb + sx0);
            bk1[tc] = *(const short8*)(ksr + rb + sx1);
        }

        short4v pk[2][4];
        bool act[2];
        #pragma unroll
        for (int g = 0; g < 2; ++g) {
            const int gb = q0 + g * 64 + 16 * w;     // wave-uniform
            act[g] = (kt * 64 <= gb + 15);
            if (act[g]) {
                // S^T = K * Q^T  (A = K tile rows=keys, B = Q strip cols=queries)
                floatx4 sacc[4];
                #pragma unroll
                for (int tc = 0; tc < 4; ++tc) {
                    sacc[tc] = __builtin_amdgcn_mfma_f32_16x16x32_bf16(bk0[tc], aq[g][0], zero, 0, 0, 0);
                    sacc[tc] = __builtin_amdgcn_mfma_f32_16x16x32_bf16(bk1[tc], aq[g][1], sacc[tc], 0, 0, 0);
                }
                if (kt * 64 + 63 > gb) {             // diagonal tile: mask
                    int qrow = gb + lcol;
                    #pragma unroll
                    for (int tc = 0; tc < 4; ++tc) {
                        float p[4];
                        #pragma unroll
                        for (int r = 0; r < 4; ++r) {
                            float e = __builtin_amdgcn_exp2f(sacc[tc][r] * SC);
                            p[r] = (kt * 64 + tc * 16 + quad * 4 + r > qrow) ? 0.f : e;
                        }
                        pk[g][tc] = pack4bf(p[0], p[1], p[2], p[3]);
                    }
                } else {
                    #pragma unroll
                    for (int tc = 0; tc < 4; ++tc) {
                        pk[g][tc] = pack4bf(
                            __builtin_amdgcn_exp2f(sacc[tc][0] * SC),
                            __builtin_amdgcn_exp2f(sacc[tc][1] * SC),
                            __builtin_amdgcn_exp2f(sacc[tc][2] * SC),
                            __builtin_amdgcn_exp2f(sacc[tc][3] * SC));
                    }
                }
            }
        }

        // O^T += V^T * P^T  -- V frags read ONCE, consumed by both groups
        #pragma unroll
        for (int td = 0; td < 4; ++td) {
            short4v va[4];
            #pragma unroll
            for (int tc = 0; tc < 4; ++tc) {
                int seg = ((tc << 1) + (quad >> 1)) ^ (lcol & 7);
                va[tc] = *(const short4v*)(vsr + ((td * 16 + lcol) << 6) + (seg << 3) + ((quad & 1) << 2));
            }
            if (act[0]) {
                #pragma unroll
                for (int tc = 0; tc < 4; ++tc)
                    O[0][td] = MFMA16K16(va[tc], pk[0][tc], O[0][td]);
            }
            if (act[1]) {
                #pragma unroll
                for (int tc = 0; tc < 4; ++tc)
                    O[1][td] = MFMA16K16(va[tc], pk[1][tc], O[1][td]);
            }
        }
        // l[q] += sum_key P^T[key][q]
        #pragma unroll
        for (int g = 0; g < 2; ++g) {
            if (act[g]) {
                #pragma unroll
                for (int tc = 0; tc < 4; ++tc)
                    lacc[g] = MFMA16K16(ones4, pk[g][tc], lacc[g]);
            }
        }
    }

    if (nc == 1) {
        // ---- single chunk: final normalize + write ----
        int b = bh >> 4, h = bh & 15;
        #pragma unroll
        for (int g = 0; g < 2; ++g) {
            int qrow = q0 + g * 64 + 16 * w + lcol;
            float inv = 1.0f / lacc[g][0];
            size_t obase = ((size_t)b * SEQ + qrow) * EMB + (size_t)h * HD + quad * 4;
            #pragma unroll
            for (int td = 0; td < 4; ++td) {
                short4v ov;
                #pragma unroll
                for (int r = 0; r < 4; ++r) ov[r] = (short)f2bf(O[g][td][r] * inv);
                *(short4v*)(&Out[obase + td * 16]) = ov;
            }
        }
    } else if (ci == 0) {
        // ---- chunk 0: RAW bf16 O into final Out rows; l into Laux ----
        int b = bh >> 4, h = bh & 15;
        float* lrow = Laux + ((size_t)bh * 12 + (qt2 - 4)) * 128;
        #pragma unroll
        for (int g = 0; g < 2; ++g) {
            int ql = g * 64 + 16 * w + lcol;
            int qrow = q0 + ql;
            size_t obase = ((size_t)b * SEQ + qrow) * EMB + (size_t)h * HD + quad * 4;
            #pragma unroll
            for (int td = 0; td < 4; ++td) {
                short4v ov;
                #pragma unroll
                for (int r = 0; r < 4; ++r) ov[r] = (short)f2bf(O[g][td][r]);
                *(short4v*)(&Out[obase + td * 16]) = ov;
            }
            if (quad == 0) lrow[ql] = lacc[g][0];
        }
    } else {
        // ---- chunks ci>=1: partial slot (raw bf16 O + f32 l) ----
        unsigned char* sp = Part
            + (size_t)(bh * SLOTS_PER_BH + slot_off(qt2, ci)) * SLOT_B;
        unsigned short* sO = (unsigned short*)sp;       // [q_local 0..127][d 0..63]
        float* sL = (float*)(sp + 16384);
        #pragma unroll
        for (int g = 0; g < 2; ++g) {
            int ql = g * 64 + 16 * w + lcol;
            #pragma unroll
            for (int td = 0; td < 4; ++td) {
                short4v ov;
                #pragma unroll
                for (int r = 0; r < 4; ++r) ov[r] = (short)f2bf(O[g][td][r]);
                *(short4v*)(&sO[ql * 64 + td * 16 + quad * 4]) = ov;
            }
            if (quad == 0) sL[ql] = lacc[g][0];
        }
    }
}

// merge chunk-0 (raw in Out + Laux) with slots 1..nc-1, normalize, rewrite Out
__global__ __launch_bounds__(256) void attn_combine(
    const unsigned char* __restrict__ Part, const float* __restrict__ Laux,
    unsigned short* __restrict__ Out)
{
    int qt2 = 4 + (int)blockIdx.x;           // 4..15
    int bh = blockIdx.y;
    int nc = 1 + (qt2 >> 2);                 // 2..4
    const unsigned char* base = Part
        + (size_t)(bh * SLOTS_PER_BH + slot_off(qt2, 1)) * SLOT_B;
    const float* lrow = Laux + ((size_t)bh * 12 + (qt2 - 4)) * 128;
    int b = bh >> 4, h = bh & 15;
    size_t obase = ((size_t)b * SEQ + qt2 * 128) * EMB + (size_t)h * HD;
    int t = threadIdx.x;
    #pragma unroll
    for (int it = 0; it < 4; ++it) {
        int job = it * 256 + t;              // 0..1023 = 128 rows x 8 col-chunks
        int row = job >> 3, c8 = (job & 7) * 8;
        unsigned short* op = &Out[obase + (size_t)row * EMB + c8];
        float acc8[8];
        short8 v0 = *(const short8*)op;      // chunk-0 raw partial
        #pragma unroll
        for (int e = 0; e < 8; ++e) acc8[e] = bf2f((unsigned short)v0[e]);
        float lsum = lrow[row];
        for (int k = 1; k < nc; ++k) {
            const unsigned char* sp = base + (size_t)(k - 1) * SLOT_B;
            const unsigned short* sO = (const unsigned short*)sp;
            const float* sL = (const float*)(sp + 16384);
            short8 vv = *(const short8*)(&sO[row * 64 + c8]);
            #pragma unroll
            for (int e = 0; e < 8; ++e) acc8[e] += bf2f((unsigned short)vv[e]);
            lsum += sL[row];
        }
        float inv = 1.0f / lsum;
        short8 ov;
        #pragma unroll
        for (int e = 0; e < 8; ++e) ov[e] = (short)f2bf(acc8[e] * inv);
        *(short8*)op = ov;
    }
}

// ---------------------------------------------------------------------------
// Output projection: single-barrier dbuf GLL K-loop. fp32 bias, fp32 out.
// ---------------------------------------------------------------------------
__global__ __launch_bounds__(256) void oproj_gemm(
    const unsigned short* __restrict__ A,    // [4096][1024] bf16
    const unsigned short* __restrict__ Bt,   // W_o^T [1024][1024] bf16
    const float* __restrict__ bias,          // [1024] fp32
    float* __restrict__ Cout)                // [4096][1024] fp32
{
    const int K = EMB;
    __shared__ __align__(16) unsigned short smem[2 * 8192];
    int t = threadIdx.x;
    int m0 = blockIdx.y * 128;
    int n0 = blockIdx.x * 128;
    int w = t >> 6, lane = t & 63, quad = lane >> 4, lcol = lane & 15;
    int wr = w >> 1, wc = w & 1;

    floatx4 zero = {0.f, 0.f, 0.f, 0.f};
    floatx4 acc[4][4];
    #pragma unroll
    for (int i = 0; i < 4; ++i)
        #pragma unroll
        for (int j = 0; j < 4; ++j) acc[i][j] = zero;

    const unsigned short* a0 = A  + (size_t)(m0 + (t >> 2)) * K + ((t & 3) << 3);
    const unsigned short* b0 = Bt + (size_t)(n0 + (t >> 2)) * K + ((t & 3) << 3);
    unsigned short* la = &smem[t << 3];

    GLL(a0, la);
    GLL(a0 + 64 * K, la + 2048);
    GLL(b0, la + 4096);
    GLL(b0 + 64 * K, la + 6144);

    for (int k0 = 0; k0 < K; k0 += 32) {
        int cur = (k0 >> 5) & 1, nxt = cur ^ 1;
        __syncthreads();
        if (k0 + 32 < K) {
            GLL(a0 + k0 + 32, la + nxt * 8192);
            GLL(a0 + 64 * K + k0 + 32, la + nxt * 8192 + 2048);
            GLL(b0 + k0 + 32, la + nxt * 8192 + 4096);
            GLL(b0 + 64 * K + k0 + 32, la + nxt * 8192 + 6144);
        }
        const unsigned short* As = &smem[cur * 8192];
        const unsigned short* Bs = As + 4096;
        short8 af[4], bfm[4];
        #pragma unroll
        for (int i = 0; i < 4; ++i)
            af[i] = *(const short8*)(&As[(wr * 64 + i * 16 + lcol) * 32 + quad * 8]);
        #pragma unroll
        for (int j = 0; j < 4; ++j)
            bfm[j] = *(const short8*)(&Bs[(wc * 64 + j * 16 + lcol) * 32 + quad * 8]);
        #pragma unroll
        for (int i = 0; i < 4; ++i)
            #pragma unroll
            for (int j = 0; j < 4; ++j)
                acc[i][j] = __builtin_amdgcn_mfma_f32_16x16x32_bf16(af[i], bfm[j], acc[i][j], 0, 0, 0);
    }

    #pragma unroll
    for (int i = 0; i < 4; ++i) {
        int m = m0 + wr * 64 + i * 16 + quad * 4;
        #pragma unroll
        for (int j = 0; j < 4; ++j) {
            int n = n0 + wc * 64 + j * 16 + lcol;
            float bv = bias[n];
            #pragma unroll
            for (int r = 0; r < 4; ++r)
                Cout[(size_t)(m + r) * EMB + n] = acc[i][j][r] + bv;
        }
    }
}

// ---------------------------------------------------------------------------
extern "C" void kernel_launch(void* const* d_in, const int* in_sizes, int n_in,
                              void* d_out, int out_size, void* d_ws, size_t ws_size,
                              hipStream_t stream) {
    (void)in_sizes; (void)n_in; (void)out_size; (void)ws_size;
    char* ws = (char*)d_ws;
    const size_t OFF_X     = 0;                                      // 8 MB
    const size_t OFF_WQKVT = OFF_X     + (size_t)M_ROWS * EMB * 2;   // 6 MB
    const size_t OFF_WOT   = OFF_WQKVT + (size_t)N_QKV * EMB * 2;    // 2 MB
    const size_t OFF_Q     = OFF_WOT   + (size_t)EMB * EMB * 2;      // 8 MB
    const size_t OFF_K     = OFF_Q     + (size_t)M_ROWS * EMB * 2;   // 8 MB
    const size_t OFF_V     = OFF_K     + (size_t)M_ROWS * EMB * 2;   // 8 MB
    const size_t OFF_ATTN  = OFF_V     + (size_t)M_ROWS * EMB * 2;   // 8 MB
    // Partials OVERLAY x_bf+wqkvT (dead after qkv_gemm). 12.97MB + 0.19MB
    // fits in the 14MB region; woT at +14MB untouched. Total ws use: 48MB.
    const size_t OFF_PART  = OFF_X;
    const size_t OFF_LAUX  = OFF_PART + (size_t)32 * SLOTS_PER_BH * SLOT_B;

    const float* x    = (const float*)d_in[0];
    const float* Wqkv = (const float*)d_in[1];
    const float* bqkv = (const float*)d_in[2];
    const float* Wo   = (const float*)d_in[3];
    const float* bo   = (const float*)d_in[4];

    unsigned short* x_bf  = (unsigned short*)(ws + OFF_X);
    unsigned short* wqkvT = (unsigned short*)(ws + OFF_WQKVT);
    unsigned short* woT   = (unsigned short*)(ws + OFF_WOT);
    unsigned short* qb    = (unsigned short*)(ws + OFF_Q);
    unsigned short* kb    = (unsigned short*)(ws + OFF_K);
    unsigned short* vb    = (unsigned short*)(ws + OFF_V);    // [B,H,D,S]
    unsigned short* attn  = (unsigned short*)(ws + OFF_ATTN);
    unsigned char*  part  = (unsigned char*)(ws + OFF_PART);
    float*          laux  = (float*)(ws + OFF_LAUX);

    prep<<<dim3(96, 32, 3), dim3(32, 8), 0, stream>>>(x, Wqkv, Wo, x_bf, wqkvT, woT);

    qkv_gemm<<<dim3(N_QKV / 128, M_ROWS / 128), 256, 0, stream>>>(x_bf, wqkvT, bqkv, qb, kb, vb);
    attn_fused<<<dim3(40, NB * NH), 256, 0, stream>>>(qb, kb, vb, attn, part, laux);
    attn_combine<<<dim3(12, NB * NH), 256, 0, stream>>>(part, laux, attn);
    oproj_gemm<<<dim3(EMB / 128, M_ROWS / 128), 256, 0, stream>>>(attn, woT, bo, (float*)d_out);
}

// Round 5
// 198.131 us; speedup vs baseline: 1.8284x; 1.0145x over previous
//
#include <hip/hip_runtime.h>

// ---------------------------------------------------------------------------
// MultiHeadAttention: B=2, S=2048, E=1024, H=16, D=64, causal. fp32 I/O.
// R16: attention latency-hiding restructure (R15 diagnosis: ~1 block/CU ->
// 1 wave/SIMD -> per-tile 3840cy vs ~1500cy of pipe work; __syncthreads
// vmcnt(0) drain per tile).
//   - 512-thread blocks (8 waves), QBLK=256: wave w owns rows q0+128g+16w,
//     g=0,1. K/V LDS reads amortize over 32 queries/wave (same LDS floor),
//     but >=2 waves/SIMD even at 1 block/CU.
//   - Counted-vmcnt pipeline: Ks[3]/Vs[3] (48KB), depth-2 prefetch, ONE raw
//     s_barrier per tile after s_waitcnt vmcnt(2) (vmcnt(0) only last tile).
//     Loads stay in flight across barriers (T3/T4); no per-tile drain.
//   - Balanced split-K: nt=4(qt3+1) tiles, nc=ceil((qt3+1)/2) -> chunks of
//     6-8 tiles, 640 blocks, LPT-ordered map, XCD pinned to 4 heads.
//   - Partials: chunk 0 raw bf16 O -> Out rows + l -> Laux; ci>=1 -> slots
//     (12/bh x 33KB = 12.97MB) overlaying x_bf/wqkvT. Footprint 48MB.
// GEMMs / prep unchanged.
// ---------------------------------------------------------------------------

typedef __attribute__((ext_vector_type(8))) short short8;
typedef __attribute__((ext_vector_type(4))) short short4v;
typedef __attribute__((ext_vector_type(4))) float floatx4;

#define NB 2
#define SEQ 2048
#define EMB 1024
#define NH 16
#define HD 64
#define M_ROWS (NB * SEQ)        // 4096
#define N_QKV (3 * EMB)          // 3072
#define SLOT_B 33792             // 256x64 bf16 O (32768) + 256 fp32 l (1024)
#define SLOTS_PER_BH 12          // chunks ci>=1 only

#define GLL(g, l) __builtin_amdgcn_global_load_lds( \
    (const __attribute__((address_space(1))) void*)(g), \
    (__attribute__((address_space(3))) void*)(l), 16, 0, 0)

#if defined(__HIP_DEVICE_COMPILE__)
#define MFMA16K16(A, B, C) __builtin_amdgcn_mfma_f32_16x16x16bf16_1k(A, B, C, 0, 0, 0)
#else
#define MFMA16K16(A, B, C) (C)   // host pass parses but never executes this
#endif

static __device__ __forceinline__ unsigned short f2bf(float f) {
    union { float f; unsigned int u; } v; v.f = f;
    unsigned int r = v.u + 0x7FFFu + ((v.u >> 16) & 1u);
    return (unsigned short)(r >> 16);
}
static __device__ __forceinline__ float bf2f(unsigned short h) {
    union { unsigned int u; float f; } v; v.u = ((unsigned int)h) << 16;
    return v.f;
}

// packed f32x2 -> bf16x2 (RNE) in one HW instruction
static __device__ __forceinline__ unsigned int cvt_pk_bf16(float lo, float hi) {
#if defined(__HIP_DEVICE_COMPILE__)
    unsigned int r;
    asm("v_cvt_pk_bf16_f32 %0, %1, %2" : "=v"(r) : "v"(lo), "v"(hi));
    return r;
#else
    (void)lo; (void)hi; return 0u;  // host pass never executes
#endif
}
static __device__ __forceinline__ short4v pack4bf(float a, float b, float c, float d) {
    union { unsigned int u[2]; short4v s; } pu;
    pu.u[0] = cvt_pk_bf16(a, b);
    pu.u[1] = cvt_pk_bf16(c, d);
    return pu.s;
}

// Chunk schedule (qq = 0..19), LPT order (size-8 chunks first).
// nt=4(qt3+1), nc=ceil((qt3+1)/2); every (qt3,ci), ci<nc, appears once.
__constant__ unsigned char FQT[20] = {
    1,3,3,5,5,5,7,7,7,7, 4,4,6,6,6,6, 2,2,4, 0 };
__constant__ unsigned char FCI[20] = {
    0,0,1,0,1,2,0,1,2,3, 1,2,0,1,2,3, 0,1,0, 0 };

// slot offset within a bh for (qt3>=2, ci>=1): 12 slots total
static __device__ __forceinline__ int slot_off(int qt3, int ci) {
    int so = (qt3 < 4) ? (qt3 - 2)
           : (qt3 < 6 ? 2 + (qt3 - 4) * 2 : 6 + (qt3 - 6) * 3);
    return so + (ci - 1);
}

// Fused prep: z=0 transpose W_qkv, z=1 transpose W_o, z=2 convert x -> bf16.
__global__ void prep(const float* __restrict__ x,
                     const float* __restrict__ Wqkv, const float* __restrict__ Wo,
                     unsigned short* __restrict__ x_bf,
                     unsigned short* __restrict__ wqkvT, unsigned short* __restrict__ woT) {
    __shared__ unsigned short tile[32][33];
    int z = blockIdx.z;
    int tx = threadIdx.x, ty = threadIdx.y;
    if (z == 2) {
        int id = ((int)blockIdx.y * 96 + (int)blockIdx.x) * 256 + ty * 32 + tx;
        const int n4 = M_ROWS * EMB / 4;
        for (int i = id; i < n4; i += 96 * 32 * 256) {
            float4 v = ((const float4*)x)[i];
            unsigned long long p = (unsigned long long)f2bf(v.x)
                | ((unsigned long long)f2bf(v.y) << 16)
                | ((unsigned long long)f2bf(v.z) << 32)
                | ((unsigned long long)f2bf(v.w) << 48);
            ((unsigned long long*)x_bf)[i] = p;
        }
        return;
    }
    int C = z ? EMB : N_QKV;
    if ((int)blockIdx.x * 32 >= C) return;
    const float* in = z ? Wo : Wqkv;
    unsigned short* out = z ? woT : wqkvT;
    const int R = EMB;
    int c0 = blockIdx.x * 32, r0 = blockIdx.y * 32;
    #pragma unroll
    for (int j = 0; j < 4; ++j)
        tile[ty + j * 8][tx] = f2bf(in[(size_t)(r0 + ty + j * 8) * C + c0 + tx]);
    __syncthreads();
    #pragma unroll
    for (int j = 0; j < 4; ++j)
        out[(size_t)(c0 + ty + j * 8) * R + r0 + tx] = tile[tx][ty + j * 8];
}

// ---------------------------------------------------------------------------
// QKV GEMM: single-barrier dbuf GLL K-loop + LDS-roundtrip coalesced epilogue.
// Q,K -> [B,H,S,D]; V -> [B,H,D,S].
// ---------------------------------------------------------------------------
#define CTS 130   // C-tile LDS stride (shorts), pad 2

__global__ __launch_bounds__(256) void qkv_gemm(
    const unsigned short* __restrict__ A,    // x_bf [4096][1024]
    const unsigned short* __restrict__ Bt,   // W_qkv^T [3072][1024] bf16
    const float* __restrict__ bias,          // [3072] fp32
    unsigned short* __restrict__ qb, unsigned short* __restrict__ kb,
    unsigned short* __restrict__ vb)         // vb: [B,H,D,S]
{
    const int K = EMB;
    __shared__ __align__(16) unsigned short smem[128 * CTS];

    int t = threadIdx.x;
    int m0 = blockIdx.y * 128;
    int n0 = blockIdx.x * 128;
    int w = t >> 6, lane = t & 63, quad = lane >> 4, lcol = lane & 15;
    int wr = w >> 1, wc = w & 1;

    floatx4 zero = {0.f, 0.f, 0.f, 0.f};
    floatx4 acc[4][4];
    #pragma unroll
    for (int i = 0; i < 4; ++i)
        #pragma unroll
        for (int j = 0; j < 4; ++j) acc[i][j] = zero;

    const unsigned short* a0 = A  + (size_t)(m0 + (t >> 2)) * K + ((t & 3) << 3);
    const unsigned short* b0 = Bt + (size_t)(n0 + (t >> 2)) * K + ((t & 3) << 3);
    unsigned short* la = &smem[t << 3];          // + buf*8192 ; Bs at +4096

    GLL(a0, la);
    GLL(a0 + 64 * K, la + 2048);
    GLL(b0, la + 4096);
    GLL(b0 + 64 * K, la + 6144);

    for (int k0 = 0; k0 < K; k0 += 32) {
        int cur = (k0 >> 5) & 1, nxt = cur ^ 1;
        __syncthreads();                         // drains cur's staging loads
        if (k0 + 32 < K) {                       // prefetch nxt AFTER barrier
            GLL(a0 + k0 + 32, la + nxt * 8192);
            GLL(a0 + 64 * K + k0 + 32, la + nxt * 8192 + 2048);
            GLL(b0 + k0 + 32, la + nxt * 8192 + 4096);
            GLL(b0 + 64 * K + k0 + 32, la + nxt * 8192 + 6144);
        }
        const unsigned short* As = &smem[cur * 8192];
        const unsigned short* Bs = As + 4096;
        short8 af[4], bfm[4];
        #pragma unroll
        for (int i = 0; i < 4; ++i)
            af[i] = *(const short8*)(&As[(wr * 64 + i * 16 + lcol) * 32 + quad * 8]);
        #pragma unroll
        for (int j = 0; j < 4; ++j)
            bfm[j] = *(const short8*)(&Bs[(wc * 64 + j * 16 + lcol) * 32 + quad * 8]);
        #pragma unroll
        for (int i = 0; i < 4; ++i)
            #pragma unroll
            for (int j = 0; j < 4; ++j)
                acc[i][j] = __builtin_amdgcn_mfma_f32_16x16x32_bf16(af[i], bfm[j], acc[i][j], 0, 0, 0);
    }

    // ---- epilogue: bias + bf16 into LDS C-tile, then coalesced streams ----
    bool isV = (n0 >= 2 * EMB);
    __syncthreads();
    #pragma unroll
    for (int i = 0; i < 4; ++i) {
        int row0 = wr * 64 + i * 16 + quad * 4;
        #pragma unroll
        for (int j = 0; j < 4; ++j) {
            int col = wc * 64 + j * 16 + lcol;
            float bv = bias[n0 + col];
            #pragma unroll
            for (int r = 0; r < 4; ++r) {
                unsigned short hv = f2bf(acc[i][j][r] + bv);
                if (isV) smem[col * CTS + row0 + r] = hv;   // [feature][token]
                else     smem[(row0 + r) * CTS + col] = hv; // [token][feature]
            }
        }
    }
    __syncthreads();

    int b = m0 >> 11, s0 = m0 & 2047;
    int hbase = (n0 & 1023) >> 6;
    if (!isV) {
        unsigned short* dst = (n0 >= EMB) ? kb : qb;
        #pragma unroll
        for (int it = 0; it < 8; ++it) {
            int job = it * 32 + (t >> 3);
            int tok = job & 127, hh = job >> 7;
            int chunk = t & 7;
            short8 vv = *(const short8*)(&smem[tok * CTS + hh * 64 + chunk * 8]);
            size_t g = ((size_t)((b * NH + hbase + hh) * SEQ + s0 + tok)) * HD + chunk * 8;
            *(short8*)(&dst[g]) = vv;
        }
    } else {
        #pragma unroll
        for (int it = 0; it < 8; ++it) {
            int job = it * 32 + (t >> 3);
            int f = job & 127, half = job >> 7;
            int chunk = (t & 7) + half * 8;
            short8 vv = *(const short8*)(&smem[f * CTS + chunk * 8]);
            int h = hbase + (f >> 6), d = f & 63;
            size_t g = ((size_t)((b * NH + h) * HD + d)) * SEQ + s0 + chunk * 8;
            *(short8*)(&vb[g]) = vv;
        }
    }
}

// ---------------------------------------------------------------------------
// Causal flash attention, QBLK=256, 8 waves, balanced split-K (6-8 tiles).
// Wave w owns query groups gb = q0 + 128g + 16w, g=0,1. Per 64-key tile:
// S^T = K*Q^T, P^T packed bf16 via cvt_pk (direct 16x16x16 B-frag),
// O^T += V^T*P^T (V frags read once per wave, both groups), l via ones-MFMA.
// Counted-vmcnt pipeline: 3 buffers, depth-2 prefetch, raw s_barrier after
// s_waitcnt vmcnt(2) (vmcnt(0) only on last tile) -- no per-tile drain.
// ---------------------------------------------------------------------------
__global__ __launch_bounds__(512) void attn_fused(
    const unsigned short* __restrict__ Q,   // [B*H][S][D]
    const unsigned short* __restrict__ Kk,  // [B*H][S][D]
    const unsigned short* __restrict__ Vt,  // [B*H][D][S]
    unsigned short* __restrict__ Out,       // [b][s][h*64+d]
    unsigned char* __restrict__ Part,       // 12 slots per bh (ci>=1)
    float* __restrict__ Laux)               // [bh][qt3-2][256] chunk-0 l
{
    __shared__ __align__(16) unsigned short Ks[3][64 * 64];
    __shared__ __align__(16) unsigned short Vs[3][64 * 64];

    // ---- dispatch map: fid -> (bh, chunk); XCD fid%8 pinned to 4 heads ----
    int fid = (int)blockIdx.y * 20 + (int)blockIdx.x;   // 0..639
    int bh  = (fid & 7) * 4 + ((fid >> 3) & 3);
    int qq  = fid >> 5;                                 // 0..19
    int qt3 = FQT[qq];
    int ci  = FCI[qq];
    int nc  = (qt3 + 2) >> 1;                           // ceil((qt3+1)/2)
    int nt  = 4 * (qt3 + 1);                            // 64-key tiles total
    int t0  = (nt * ci) / nc, t1 = (nt * (ci + 1)) / nc;
    int q0  = qt3 * 256;

    int t = threadIdx.x;
    int w = t >> 6, lane = t & 63, quad = lane >> 4, lcol = lane & 15;
    const size_t hoff = (size_t)bh * SEQ * HD;
    const float SC = 0.18033688011112043f;   // (1/sqrt(64)) * log2(e)

    // Q strips (B-operand), two 16-row groups per wave: rows q0+128g+16w
    short8 aq[2][2];
    #pragma unroll
    for (int g = 0; g < 2; ++g) {
        const unsigned short* qp = Q + hoff
            + (size_t)(q0 + g * 128 + 16 * w + lcol) * HD + quad * 8;
        aq[g][0] = *(const short8*)qp;
        aq[g][1] = *(const short8*)(qp + 32);
    }
    // drain Q loads so in-loop vmcnt counts only staging GLLs
    asm volatile("s_waitcnt vmcnt(0)" ::: "memory");

    // staging addressing: 512 threads cover a full 64x64 tile per GLL call
    int srow = t >> 3;                       // 0..63
    int ss   = (t & 7) ^ (srow & 7);         // pre-swizzled global source
    const unsigned short* kgl = Kk + hoff + (size_t)srow * HD + ss * 8;
    const unsigned short* vgl = Vt + hoff + (size_t)srow * SEQ + ss * 8;
    unsigned short* kld = &Ks[0][t * 8];
    unsigned short* vld = &Vs[0][t * 8];

#define STAGE(kt_, buf_) do { \
        size_t kk_ = (size_t)(kt_) * 64; \
        GLL(kgl + kk_ * HD, kld + (buf_) * 4096); \
        GLL(vgl + kk_,      vld + (buf_) * 4096); \
    } while (0)

    floatx4 zero = {0.f, 0.f, 0.f, 0.f};
    floatx4 O[2][4];                 // O^T: row=d(quad*4+r in td*16), col=query lcol
    floatx4 lacc[2];                 // all rows = l[query lcol]
    #pragma unroll
    for (int g = 0; g < 2; ++g) {
        lacc[g] = zero;
        #pragma unroll
        for (int td = 0; td < 4; ++td) O[g][td] = zero;
    }

    short4v ones4;
    #pragma unroll
    for (int jj = 0; jj < 4; ++jj) ones4[jj] = (short)0x3F80;  // bf16 1.0

    // prologue: stage t0 and t0+1 (all chunks have >= 4 tiles)
    STAGE(t0, t0 % 3);
    if (t0 + 1 < t1) STAGE(t0 + 1, (t0 + 1) % 3);

    int sx0 = (quad ^ (lcol & 7)) << 3;
    int sx1 = sx0 ^ 32;

    for (int kt = t0; kt < t1; ++kt) {
        // wait for tile kt's 2 GLLs (FIFO): outstanding {kt:2, kt+1:2}
        if (kt + 1 < t1) asm volatile("s_waitcnt vmcnt(2)" ::: "memory");
        else             asm volatile("s_waitcnt vmcnt(0)" ::: "memory");
        __builtin_amdgcn_s_barrier();
        __builtin_amdgcn_sched_barrier(0);

        int b3 = kt % 3;
        const unsigned short* ksr = &Ks[b3][0];
        const unsigned short* vsr = &Vs[b3][0];

        short4v pk[2][4];
        bool act[2];
        #pragma unroll
        for (int g = 0; g < 2; ++g) {
            const int gb = q0 + g * 128 + 16 * w;    // wave-uniform
            act[g] = (kt * 64 <= gb + 15);
            if (act[g]) {
                short8 bk0[4], bk1[4];
                #pragma unroll
                for (int tc = 0; tc < 4; ++tc) {
                    int rb = (tc * 16 + lcol) << 6;
                    bk0[tc] = *(const short8*)(ksr + rb + sx0);
                    bk1[tc] = *(const short8*)(ksr + rb + sx1);
                }
                // S^T = K * Q^T
                floatx4 sacc[4];
                #pragma unroll
                for (int tc = 0; tc < 4; ++tc) {
                    sacc[tc] = __builtin_amdgcn_mfma_f32_16x16x32_bf16(bk0[tc], aq[g][0], zero, 0, 0, 0);
                    sacc[tc] = __builtin_amdgcn_mfma_f32_16x16x32_bf16(bk1[tc], aq[g][1], sacc[tc], 0, 0, 0);
                }
                if (kt * 64 + 63 > gb) {             // diagonal tile: mask
                    int qrow = gb + lcol;
                    #pragma unroll
                    for (int tc = 0; tc < 4; ++tc) {
                        float p[4];
                        #pragma unroll
                        for (int r = 0; r < 4; ++r) {
                            float e = __builtin_amdgcn_exp2f(sacc[tc][r] * SC);
                            p[r] = (kt * 64 + tc * 16 + quad * 4 + r > qrow) ? 0.f : e;
                        }
                        pk[g][tc] = pack4bf(p[0], p[1], p[2], p[3]);
                    }
                } else {
                    #pragma unroll
                    for (int tc = 0; tc < 4; ++tc) {
                        pk[g][tc] = pack4bf(
                            __builtin_amdgcn_exp2f(sacc[tc][0] * SC),
                            __builtin_amdgcn_exp2f(sacc[tc][1] * SC),
                            __builtin_amdgcn_exp2f(sacc[tc][2] * SC),
                            __builtin_amdgcn_exp2f(sacc[tc][3] * SC));
                    }
                }
            }
        }

        // O^T += V^T * P^T  -- V frags read ONCE per wave, both groups
        if (act[0]) {
            #pragma unroll
            for (int td = 0; td < 4; ++td) {
                short4v va[4];
                #pragma unroll
                for (int tc = 0; tc < 4; ++tc) {
                    int seg = ((tc << 1) + (quad >> 1)) ^ (lcol & 7);
                    va[tc] = *(const short4v*)(vsr + ((td * 16 + lcol) << 6) + (seg << 3) + ((quad & 1) << 2));
                }
                #pragma unroll
                for (int tc = 0; tc < 4; ++tc)
                    O[0][td] = MFMA16K16(va[tc], pk[0][tc], O[0][td]);
                if (act[1]) {
                    #pragma unroll
                    for (int tc = 0; tc < 4; ++tc)
                        O[1][td] = MFMA16K16(va[tc], pk[1][tc], O[1][td]);
                }
            }
        } else if (act[1]) {
            #pragma unroll
            for (int td = 0; td < 4; ++td) {
                short4v va[4];
                #pragma unroll
                for (int tc = 0; tc < 4; ++tc) {
                    int seg = ((tc << 1) + (quad >> 1)) ^ (lcol & 7);
                    va[tc] = *(const short4v*)(vsr + ((td * 16 + lcol) << 6) + (seg << 3) + ((quad & 1) << 2));
                }
                #pragma unroll
                for (int tc = 0; tc < 4; ++tc)
                    O[1][td] = MFMA16K16(va[tc], pk[1][tc], O[1][td]);
            }
        }
        // l[q] += sum_key P^T[key][q]
        #pragma unroll
        for (int g = 0; g < 2; ++g) {
            if (act[g]) {
                #pragma unroll
                for (int tc = 0; tc < 4; ++tc)
                    lacc[g] = MFMA16K16(ones4, pk[g][tc], lacc[g]);
            }
        }

        __builtin_amdgcn_sched_barrier(0);
        if (kt + 2 < t1) STAGE(kt + 2, (kt + 2) % 3);   // buf (kt+2)%3 == (kt-1)%3: readers done
    }
#undef STAGE

    if (nc == 1) {
        // ---- single chunk (qt3 0,1): final normalize + write ----
        int b = bh >> 4, h = bh & 15;
        #pragma unroll
        for (int g = 0; g < 2; ++g) {
            int qrow = q0 + g * 128 + 16 * w + lcol;
            float inv = 1.0f / lacc[g][0];
            size_t obase = ((size_t)b * SEQ + qrow) * EMB + (size_t)h * HD + quad * 4;
            #pragma unroll
            for (int td = 0; td < 4; ++td) {
                short4v ov;
                #pragma unroll
                for (int r = 0; r < 4; ++r) ov[r] = (short)f2bf(O[g][td][r] * inv);
                *(short4v*)(&Out[obase + td * 16]) = ov;
            }
        }
    } else if (ci == 0) {
        // ---- chunk 0: RAW bf16 O into final Out rows; l into Laux ----
        int b = bh >> 4, h = bh & 15;
        float* lrow = Laux + ((size_t)bh * 6 + (qt3 - 2)) * 256;
        #pragma unroll
        for (int g = 0; g < 2; ++g) {
            int ql = g * 128 + 16 * w + lcol;
            int qrow = q0 + ql;
            size_t obase = ((size_t)b * SEQ + qrow) * EMB + (size_t)h * HD + quad * 4;
            #pragma unroll
            for (int td = 0; td < 4; ++td) {
                short4v ov;
                #pragma unroll
                for (int r = 0; r < 4; ++r) ov[r] = (short)f2bf(O[g][td][r]);
                *(short4v*)(&Out[obase + td * 16]) = ov;
            }
            if (quad == 0) lrow[ql] = lacc[g][0];
        }
    } else {
        // ---- chunks ci>=1: partial slot (raw bf16 O + f32 l) ----
        unsigned char* sp = Part
            + (size_t)(bh * SLOTS_PER_BH + slot_off(qt3, ci)) * SLOT_B;
        unsigned short* sO = (unsigned short*)sp;       // [q_local 0..255][d 0..63]
        float* sL = (float*)(sp + 32768);
        #pragma unroll
        for (int g = 0; g < 2; ++g) {
            int ql = g * 128 + 16 * w + lcol;
            #pragma unroll
            for (int td = 0; td < 4; ++td) {
                short4v ov;
                #pragma unroll
                for (int r = 0; r < 4; ++r) ov[r] = (short)f2bf(O[g][td][r]);
                *(short4v*)(&sO[ql * 64 + td * 16 + quad * 4]) = ov;
            }
            if (quad == 0) sL[ql] = lacc[g][0];
        }
    }
}

// merge chunk-0 (raw in Out + Laux) with slots 1..nc-1, normalize, rewrite Out
__global__ __launch_bounds__(256) void attn_combine(
    const unsigned char* __restrict__ Part, const float* __restrict__ Laux,
    unsigned short* __restrict__ Out)
{
    int qt3 = 2 + (int)blockIdx.x;           // 2..7
    int bh = blockIdx.y;
    int nc = (qt3 + 2) >> 1;                 // 2..4
    const unsigned char* base = Part
        + (size_t)(bh * SLOTS_PER_BH + slot_off(qt3, 1)) * SLOT_B;
    const float* lrow = Laux + ((size_t)bh * 6 + (qt3 - 2)) * 256;
    int b = bh >> 4, h = bh & 15;
    size_t obase = ((size_t)b * SEQ + qt3 * 256) * EMB + (size_t)h * HD;
    int t = threadIdx.x;
    #pragma unroll
    for (int it = 0; it < 8; ++it) {
        int job = it * 256 + t;              // 0..2047 = 256 rows x 8 col-chunks
        int row = job >> 3, c8 = (job & 7) * 8;
        unsigned short* op = &Out[obase + (size_t)row * EMB + c8];
        float acc8[8];
        short8 v0 = *(const short8*)op;      // chunk-0 raw partial
        #pragma unroll
        for (int e = 0; e < 8; ++e) acc8[e] = bf2f((unsigned short)v0[e]);
        float lsum = lrow[row];
        for (int k = 1; k < nc; ++k) {
            const unsigned char* sp = base + (size_t)(k - 1) * SLOT_B;
            const unsigned short* sO = (const unsigned short*)sp;
            const float* sL = (const float*)(sp + 32768);
            short8 vv = *(const short8*)(&sO[row * 64 + c8]);
            #pragma unroll
            for (int e = 0; e < 8; ++e) acc8[e] += bf2f((unsigned short)vv[e]);
            lsum += sL[row];
        }
        float inv = 1.0f / lsum;
        short8 ov;
        #pragma unroll
        for (int e = 0; e < 8; ++e) ov[e] = (short)f2bf(acc8[e] * inv);
        *(short8*)op = ov;
    }
}

// ---------------------------------------------------------------------------
// Output projection: single-barrier dbuf GLL K-loop. fp32 bias, fp32 out.
// ---------------------------------------------------------------------------
__global__ __launch_bounds__(256) void oproj_gemm(
    const unsigned short* __restrict__ A,    // [4096][1024] bf16
    const unsigned short* __restrict__ Bt,   // W_o^T [1024][1024] bf16
    const float* __restrict__ bias,          // [1024] fp32
    float* __restrict__ Cout)                // [4096][1024] fp32
{
    const int K = EMB;
    __shared__ __align__(16) unsigned short smem[2 * 8192];
    int t = threadIdx.x;
    int m0 = blockIdx.y * 128;
    int n0 = blockIdx.x * 128;
    int w = t >> 6, lane = t & 63, quad = lane >> 4, lcol = lane & 15;
    int wr = w >> 1, wc = w & 1;

    floatx4 zero = {0.f, 0.f, 0.f, 0.f};
    floatx4 acc[4][4];
    #pragma unroll
    for (int i = 0; i < 4; ++i)
        #pragma unroll
        for (int j = 0; j < 4; ++j) acc[i][j] = zero;

    const unsigned short* a0 = A  + (size_t)(m0 + (t >> 2)) * K + ((t & 3) << 3);
    const unsigned short* b0 = Bt + (size_t)(n0 + (t >> 2)) * K + ((t & 3) << 3);
    unsigned short* la = &smem[t << 3];

    GLL(a0, la);
    GLL(a0 + 64 * K, la + 2048);
    GLL(b0, la + 4096);
    GLL(b0 + 64 * K, la + 6144);

    for (int k0 = 0; k0 < K; k0 += 32) {
        int cur = (k0 >> 5) & 1, nxt = cur ^ 1;
        __syncthreads();
        if (k0 + 32 < K) {
            GLL(a0 + k0 + 32, la + nxt * 8192);
            GLL(a0 + 64 * K + k0 + 32, la + nxt * 8192 + 2048);
            GLL(b0 + k0 + 32, la + nxt * 8192 + 4096);
            GLL(b0 + 64 * K + k0 + 32, la + nxt * 8192 + 6144);
        }
        const unsigned short* As = &smem[cur * 8192];
        const unsigned short* Bs = As + 4096;
        short8 af[4], bfm[4];
        #pragma unroll
        for (int i = 0; i < 4; ++i)
            af[i] = *(const short8*)(&As[(wr * 64 + i * 16 + lcol) * 32 + quad * 8]);
        #pragma unroll
        for (int j = 0; j < 4; ++j)
            bfm[j] = *(const short8*)(&Bs[(wc * 64 + j * 16 + lcol) * 32 + quad * 8]);
        #pragma unroll
        for (int i = 0; i < 4; ++i)
            #pragma unroll
            for (int j = 0; j < 4; ++j)
                acc[i][j] = __builtin_amdgcn_mfma_f32_16x16x32_bf16(af[i], bfm[j], acc[i][j], 0, 0, 0);
    }

    #pragma unroll
    for (int i = 0; i < 4; ++i) {
        int m = m0 + wr * 64 + i * 16 + quad * 4;
        #pragma unroll
        for (int j = 0; j < 4; ++j) {
            int n = n0 + wc * 64 + j * 16 + lcol;
            float bv = bias[n];
            #pragma unroll
            for (int r = 0; r < 4; ++r)
                Cout[(size_t)(m + r) * EMB + n] = acc[i][j][r] + bv;
        }
    }
}

// ---------------------------------------------------------------------------
extern "C" void kernel_launch(void* const* d_in, const int* in_sizes, int n_in,
                              void* d_out, int out_size, void* d_ws, size_t ws_size,
                              hipStream_t stream) {
    (void)in_sizes; (void)n_in; (void)out_size; (void)ws_size;
    char* ws = (char*)d_ws;
    const size_t OFF_X     = 0;                                      // 8 MB
    const size_t OFF_WQKVT = OFF_X     + (size_t)M_ROWS * EMB * 2;   // 6 MB
    const size_t OFF_WOT   = OFF_WQKVT + (size_t)N_QKV * EMB * 2;    // 2 MB
    const size_t OFF_Q     = OFF_WOT   + (size_t)EMB * EMB * 2;      // 8 MB
    const size_t OFF_K     = OFF_Q     + (size_t)M_ROWS * EMB * 2;   // 8 MB
    const size_t OFF_V     = OFF_K     + (size_t)M_ROWS * EMB * 2;   // 8 MB
    const size_t OFF_ATTN  = OFF_V     + (size_t)M_ROWS * EMB * 2;   // 8 MB
    // Partials OVERLAY x_bf+wqkvT (dead after qkv_gemm). 12.97MB + 0.19MB
    // fits in the 14MB region; woT at +14MB untouched. Total ws use: 48MB.
    const size_t OFF_PART  = OFF_X;
    const size_t OFF_LAUX  = OFF_PART + (size_t)32 * SLOTS_PER_BH * SLOT_B;

    const float* x    = (const float*)d_in[0];
    const float* Wqkv = (const float*)d_in[1];
    const float* bqkv = (const float*)d_in[2];
    const float* Wo   = (const float*)d_in[3];
    const float* bo   = (const float*)d_in[4];

    unsigned short* x_bf  = (unsigned short*)(ws + OFF_X);
    unsigned short* wqkvT = (unsigned short*)(ws + OFF_WQKVT);
    unsigned short* woT   = (unsigned short*)(ws + OFF_WOT);
    unsigned short* qb    = (unsigned short*)(ws + OFF_Q);
    unsigned short* kb    = (unsigned short*)(ws + OFF_K);
    unsigned short* vb    = (unsigned short*)(ws + OFF_V);    // [B,H,D,S]
    unsigned short* attn  = (unsigned short*)(ws + OFF_ATTN);
    unsigned char*  part  = (unsigned char*)(ws + OFF_PART);
    float*          laux  = (float*)(ws + OFF_LAUX);

    prep<<<dim3(96, 32, 3), dim3(32, 8), 0, stream>>>(x, Wqkv, Wo, x_bf, wqkvT, woT);

    qkv_gemm<<<dim3(N_QKV / 128, M_ROWS / 128), 256, 0, stream>>>(x_bf, wqkvT, bqkv, qb, kb, vb);
    attn_fused<<<dim3(20, NB * NH), 512, 0, stream>>>(qb, kb, vb, attn, part, laux);
    attn_combine<<<dim3(6, NB * NH), 256, 0, stream>>>(part, laux, attn);
    oproj_gemm<<<dim3(EMB / 128, M_ROWS / 128), 256, 0, stream>>>(attn, woT, bo, (float*)d_out);
}

// Round 7
// 193.725 us; speedup vs baseline: 1.8699x; 1.0227x over previous
//
#include <hip/hip_runtime.h>

// ---------------------------------------------------------------------------
// MultiHeadAttention: B=2, S=2048, E=1024, H=16, D=64, causal. fp32 I/O.
// R18: isolate the R17 container failure (only delta was counted-vmcnt in
// BOTH GEMMs; logic review found no bug).
//   - qkv_gemm REVERTED to the R16 2-barrier dbuf loop (known-good).
//   - oproj_gemm gets the counted-vmcnt 3-buffer pipeline, restructured to
//     EXACTLY mirror the attn loop proven on HW in R16: vmcnt(N) at top ->
//     s_barrier -> sched_barrier(0) -> compute -> sched_barrier(0) ->
//     STAGE(it+2) at end. (R17 staged between barrier and reads.)
//   - attn_fused / attn_combine / prep / launch: identical to R16 (passed).
// If this passes, pipeline-on-GEMM is validated and qkv gets it next round;
// if the profile again shows only 41us fills in the top-5 with total ~198,
// the harness re-poison floor dominates and we are at the effective ceiling.
// ---------------------------------------------------------------------------

typedef __attribute__((ext_vector_type(8))) short short8;
typedef __attribute__((ext_vector_type(4))) short short4v;
typedef __attribute__((ext_vector_type(4))) float floatx4;

#define NB 2
#define SEQ 2048
#define EMB 1024
#define NH 16
#define HD 64
#define M_ROWS (NB * SEQ)        // 4096
#define N_QKV (3 * EMB)          // 3072
#define SLOT_B 33792             // 256x64 bf16 O (32768) + 256 fp32 l (1024)
#define SLOTS_PER_BH 12          // chunks ci>=1 only

#define GLL(g, l) __builtin_amdgcn_global_load_lds( \
    (const __attribute__((address_space(1))) void*)(g), \
    (__attribute__((address_space(3))) void*)(l), 16, 0, 0)

#if defined(__HIP_DEVICE_COMPILE__)
#define MFMA16K16(A, B, C) __builtin_amdgcn_mfma_f32_16x16x16bf16_1k(A, B, C, 0, 0, 0)
#else
#define MFMA16K16(A, B, C) (C)   // host pass parses but never executes this
#endif

static __device__ __forceinline__ unsigned short f2bf(float f) {
    union { float f; unsigned int u; } v; v.f = f;
    unsigned int r = v.u + 0x7FFFu + ((v.u >> 16) & 1u);
    return (unsigned short)(r >> 16);
}
static __device__ __forceinline__ float bf2f(unsigned short h) {
    union { unsigned int u; float f; } v; v.u = ((unsigned int)h) << 16;
    return v.f;
}

// packed f32x2 -> bf16x2 (RNE) in one HW instruction
static __device__ __forceinline__ unsigned int cvt_pk_bf16(float lo, float hi) {
#if defined(__HIP_DEVICE_COMPILE__)
    unsigned int r;
    asm("v_cvt_pk_bf16_f32 %0, %1, %2" : "=v"(r) : "v"(lo), "v"(hi));
    return r;
#else
    (void)lo; (void)hi; return 0u;  // host pass never executes
#endif
}
static __device__ __forceinline__ short4v pack4bf(float a, float b, float c, float d) {
    union { unsigned int u[2]; short4v s; } pu;
    pu.u[0] = cvt_pk_bf16(a, b);
    pu.u[1] = cvt_pk_bf16(c, d);
    return pu.s;
}

// Chunk schedule (qq = 0..19), LPT order (size-8 chunks first).
// nt=4(qt3+1), nc=ceil((qt3+1)/2); every (qt3,ci), ci<nc, appears once.
__constant__ unsigned char FQT[20] = {
    1,3,3,5,5,5,7,7,7,7, 4,4,6,6,6,6, 2,2,4, 0 };
__constant__ unsigned char FCI[20] = {
    0,0,1,0,1,2,0,1,2,3, 1,2,0,1,2,3, 0,1,0, 0 };

// slot offset within a bh for (qt3>=2, ci>=1): 12 slots total
static __device__ __forceinline__ int slot_off(int qt3, int ci) {
    int so = (qt3 < 4) ? (qt3 - 2)
           : (qt3 < 6 ? 2 + (qt3 - 4) * 2 : 6 + (qt3 - 6) * 3);
    return so + (ci - 1);
}

// Fused prep: z=0 transpose W_qkv, z=1 transpose W_o, z=2 convert x -> bf16.
__global__ void prep(const float* __restrict__ x,
                     const float* __restrict__ Wqkv, const float* __restrict__ Wo,
                     unsigned short* __restrict__ x_bf,
                     unsigned short* __restrict__ wqkvT, unsigned short* __restrict__ woT) {
    __shared__ unsigned short tile[32][33];
    int z = blockIdx.z;
    int tx = threadIdx.x, ty = threadIdx.y;
    if (z == 2) {
        int id = ((int)blockIdx.y * 96 + (int)blockIdx.x) * 256 + ty * 32 + tx;
        const int n4 = M_ROWS * EMB / 4;
        for (int i = id; i < n4; i += 96 * 32 * 256) {
            float4 v = ((const float4*)x)[i];
            unsigned long long p = (unsigned long long)f2bf(v.x)
                | ((unsigned long long)f2bf(v.y) << 16)
                | ((unsigned long long)f2bf(v.z) << 32)
                | ((unsigned long long)f2bf(v.w) << 48);
            ((unsigned long long*)x_bf)[i] = p;
        }
        return;
    }
    int C = z ? EMB : N_QKV;
    if ((int)blockIdx.x * 32 >= C) return;
    const float* in = z ? Wo : Wqkv;
    unsigned short* out = z ? woT : wqkvT;
    const int R = EMB;
    int c0 = blockIdx.x * 32, r0 = blockIdx.y * 32;
    #pragma unroll
    for (int j = 0; j < 4; ++j)
        tile[ty + j * 8][tx] = f2bf(in[(size_t)(r0 + ty + j * 8) * C + c0 + tx]);
    __syncthreads();
    #pragma unroll
    for (int j = 0; j < 4; ++j)
        out[(size_t)(c0 + ty + j * 8) * R + r0 + tx] = tile[tx][ty + j * 8];
}

// ---------------------------------------------------------------------------
// QKV GEMM: single-barrier dbuf GLL K-loop + LDS-roundtrip coalesced epilogue.
// (R16 known-good version.) Q,K -> [B,H,S,D]; V -> [B,H,D,S].
// ---------------------------------------------------------------------------
#define CTS 130   // C-tile LDS stride (shorts), pad 2

__global__ __launch_bounds__(256) void qkv_gemm(
    const unsigned short* __restrict__ A,    // x_bf [4096][1024]
    const unsigned short* __restrict__ Bt,   // W_qkv^T [3072][1024] bf16
    const float* __restrict__ bias,          // [3072] fp32
    unsigned short* __restrict__ qb, unsigned short* __restrict__ kb,
    unsigned short* __restrict__ vb)         // vb: [B,H,D,S]
{
    const int K = EMB;
    __shared__ __align__(16) unsigned short smem[128 * CTS];

    int t = threadIdx.x;
    int m0 = blockIdx.y * 128;
    int n0 = blockIdx.x * 128;
    int w = t >> 6, lane = t & 63, quad = lane >> 4, lcol = lane & 15;
    int wr = w >> 1, wc = w & 1;

    floatx4 zero = {0.f, 0.f, 0.f, 0.f};
    floatx4 acc[4][4];
    #pragma unroll
    for (int i = 0; i < 4; ++i)
        #pragma unroll
        for (int j = 0; j < 4; ++j) acc[i][j] = zero;

    const unsigned short* a0 = A  + (size_t)(m0 + (t >> 2)) * K + ((t & 3) << 3);
    const unsigned short* b0 = Bt + (size_t)(n0 + (t >> 2)) * K + ((t & 3) << 3);
    unsigned short* la = &smem[t << 3];          // + buf*8192 ; Bs at +4096

    GLL(a0, la);
    GLL(a0 + 64 * K, la + 2048);
    GLL(b0, la + 4096);
    GLL(b0 + 64 * K, la + 6144);

    for (int k0 = 0; k0 < K; k0 += 32) {
        int cur = (k0 >> 5) & 1, nxt = cur ^ 1;
        __syncthreads();                         // drains cur's staging loads
        if (k0 + 32 < K) {                       // prefetch nxt AFTER barrier
            GLL(a0 + k0 + 32, la + nxt * 8192);
            GLL(a0 + 64 * K + k0 + 32, la + nxt * 8192 + 2048);
            GLL(b0 + k0 + 32, la + nxt * 8192 + 4096);
            GLL(b0 + 64 * K + k0 + 32, la + nxt * 8192 + 6144);
        }
        const unsigned short* As = &smem[cur * 8192];
        const unsigned short* Bs = As + 4096;
        short8 af[4], bfm[4];
        #pragma unroll
        for (int i = 0; i < 4; ++i)
            af[i] = *(const short8*)(&As[(wr * 64 + i * 16 + lcol) * 32 + quad * 8]);
        #pragma unroll
        for (int j = 0; j < 4; ++j)
            bfm[j] = *(const short8*)(&Bs[(wc * 64 + j * 16 + lcol) * 32 + quad * 8]);
        #pragma unroll
        for (int i = 0; i < 4; ++i)
            #pragma unroll
            for (int j = 0; j < 4; ++j)
                acc[i][j] = __builtin_amdgcn_mfma_f32_16x16x32_bf16(af[i], bfm[j], acc[i][j], 0, 0, 0);
    }

    // ---- epilogue: bias + bf16 into LDS C-tile, then coalesced streams ----
    bool isV = (n0 >= 2 * EMB);
    __syncthreads();
    #pragma unroll
    for (int i = 0; i < 4; ++i) {
        int row0 = wr * 64 + i * 16 + quad * 4;
        #pragma unroll
        for (int j = 0; j < 4; ++j) {
            int col = wc * 64 + j * 16 + lcol;
            float bv = bias[n0 + col];
            #pragma unroll
            for (int r = 0; r < 4; ++r) {
                unsigned short hv = f2bf(acc[i][j][r] + bv);
                if (isV) smem[col * CTS + row0 + r] = hv;   // [feature][token]
                else     smem[(row0 + r) * CTS + col] = hv; // [token][feature]
            }
        }
    }
    __syncthreads();

    int b = m0 >> 11, s0 = m0 & 2047;
    int hbase = (n0 & 1023) >> 6;
    if (!isV) {
        unsigned short* dst = (n0 >= EMB) ? kb : qb;
        #pragma unroll
        for (int it = 0; it < 8; ++it) {
            int job = it * 32 + (t >> 3);
            int tok = job & 127, hh = job >> 7;
            int chunk = t & 7;
            short8 vv = *(const short8*)(&smem[tok * CTS + hh * 64 + chunk * 8]);
            size_t g = ((size_t)((b * NH + hbase + hh) * SEQ + s0 + tok)) * HD + chunk * 8;
            *(short8*)(&dst[g]) = vv;
        }
    } else {
        #pragma unroll
        for (int it = 0; it < 8; ++it) {
            int job = it * 32 + (t >> 3);
            int f = job & 127, half = job >> 7;
            int chunk = (t & 7) + half * 8;
            short8 vv = *(const short8*)(&smem[f * CTS + chunk * 8]);
            int h = hbase + (f >> 6), d = f & 63;
            size_t g = ((size_t)((b * NH + h) * HD + d)) * SEQ + s0 + chunk * 8;
            *(short8*)(&vb[g]) = vv;
        }
    }
}

// ---------------------------------------------------------------------------
// Causal flash attention, QBLK=256, 8 waves, balanced split-K (6-8 tiles).
// Wave w owns query groups gb = q0 + 128g + 16w, g=0,1. Per 64-key tile:
// S^T = K*Q^T, P^T packed bf16 via cvt_pk (direct 16x16x16 B-frag),
// O^T += V^T*P^T (V frags read once per wave, both groups), l via ones-MFMA.
// Counted-vmcnt pipeline: 3 buffers, depth-2 prefetch, raw s_barrier after
// s_waitcnt vmcnt(2) (vmcnt(0) only on last tile) -- no per-tile drain.
// (R16 known-good version.)
// ---------------------------------------------------------------------------
__global__ __launch_bounds__(512) void attn_fused(
    const unsigned short* __restrict__ Q,   // [B*H][S][D]
    const unsigned short* __restrict__ Kk,  // [B*H][S][D]
    const unsigned short* __restrict__ Vt,  // [B*H][D][S]
    unsigned short* __restrict__ Out,       // [b][s][h*64+d]
    unsigned char* __restrict__ Part,       // 12 slots per bh (ci>=1)
    float* __restrict__ Laux)               // [bh][qt3-2][256] chunk-0 l
{
    __shared__ __align__(16) unsigned short Ks[3][64 * 64];
    __shared__ __align__(16) unsigned short Vs[3][64 * 64];

    // ---- dispatch map: fid -> (bh, chunk); XCD fid%8 pinned to 4 heads ----
    int fid = (int)blockIdx.y * 20 + (int)blockIdx.x;   // 0..639
    int bh  = (fid & 7) * 4 + ((fid >> 3) & 3);
    int qq  = fid >> 5;                                 // 0..19
    int qt3 = FQT[qq];
    int ci  = FCI[qq];
    int nc  = (qt3 + 2) >> 1;                           // ceil((qt3+1)/2)
    int nt  = 4 * (qt3 + 1);                            // 64-key tiles total
    int t0  = (nt * ci) / nc, t1 = (nt * (ci + 1)) / nc;
    int q0  = qt3 * 256;

    int t = threadIdx.x;
    int w = t >> 6, lane = t & 63, quad = lane >> 4, lcol = lane & 15;
    const size_t hoff = (size_t)bh * SEQ * HD;
    const float SC = 0.18033688011112043f;   // (1/sqrt(64)) * log2(e)

    // Q strips (B-operand), two 16-row groups per wave: rows q0+128g+16w
    short8 aq[2][2];
    #pragma unroll
    for (int g = 0; g < 2; ++g) {
        const unsigned short* qp = Q + hoff
            + (size_t)(q0 + g * 128 + 16 * w + lcol) * HD + quad * 8;
        aq[g][0] = *(const short8*)qp;
        aq[g][1] = *(const short8*)(qp + 32);
    }
    // drain Q loads so in-loop vmcnt counts only staging GLLs
    asm volatile("s_waitcnt vmcnt(0)" ::: "memory");

    // staging addressing: 512 threads cover a full 64x64 tile per GLL call
    int srow = t >> 3;                       // 0..63
    int ss   = (t & 7) ^ (srow & 7);         // pre-swizzled global source
    const unsigned short* kgl = Kk + hoff + (size_t)srow * HD + ss * 8;
    const unsigned short* vgl = Vt + hoff + (size_t)srow * SEQ + ss * 8;
    unsigned short* kld = &Ks[0][t * 8];
    unsigned short* vld = &Vs[0][t * 8];

#define STAGE(kt_, buf_) do { \
        size_t kk_ = (size_t)(kt_) * 64; \
        GLL(kgl + kk_ * HD, kld + (buf_) * 4096); \
        GLL(vgl + kk_,      vld + (buf_) * 4096); \
    } while (0)

    floatx4 zero = {0.f, 0.f, 0.f, 0.f};
    floatx4 O[2][4];                 // O^T: row=d(quad*4+r in td*16), col=query lcol
    floatx4 lacc[2];                 // all rows = l[query lcol]
    #pragma unroll
    for (int g = 0; g < 2; ++g) {
        lacc[g] = zero;
        #pragma unroll
        for (int td = 0; td < 4; ++td) O[g][td] = zero;
    }

    short4v ones4;
    #pragma unroll
    for (int jj = 0; jj < 4; ++jj) ones4[jj] = (short)0x3F80;  // bf16 1.0

    // prologue: stage t0 and t0+1 (all chunks have >= 4 tiles)
    STAGE(t0, t0 % 3);
    if (t0 + 1 < t1) STAGE(t0 + 1, (t0 + 1) % 3);

    int sx0 = (quad ^ (lcol & 7)) << 3;
    int sx1 = sx0 ^ 32;

    for (int kt = t0; kt < t1; ++kt) {
        // wait for tile kt's 2 GLLs (FIFO): outstanding {kt:2, kt+1:2}
        if (kt + 1 < t1) asm volatile("s_waitcnt vmcnt(2)" ::: "memory");
        else             asm volatile("s_waitcnt vmcnt(0)" ::: "memory");
        __builtin_amdgcn_s_barrier();
        __builtin_amdgcn_sched_barrier(0);

        int b3 = kt % 3;
        const unsigned short* ksr = &Ks[b3][0];
        const unsigned short* vsr = &Vs[b3][0];

        short4v pk[2][4];
        bool act[2];
        #pragma unroll
        for (int g = 0; g < 2; ++g) {
            const int gb = q0 + g * 128 + 16 * w;    // wave-uniform
            act[g] = (kt * 64 <= gb + 15);
            if (act[g]) {
                short8 bk0[4], bk1[4];
                #pragma unroll
                for (int tc = 0; tc < 4; ++tc) {
                    int rb = (tc * 16 + lcol) << 6;
                    bk0[tc] = *(const short8*)(ksr + rb + sx0);
                    bk1[tc] = *(const short8*)(ksr + rb + sx1);
                }
                // S^T = K * Q^T
                floatx4 sacc[4];
                #pragma unroll
                for (int tc = 0; tc < 4; ++tc) {
                    sacc[tc] = __builtin_amdgcn_mfma_f32_16x16x32_bf16(bk0[tc], aq[g][0], zero, 0, 0, 0);
                    sacc[tc] = __builtin_amdgcn_mfma_f32_16x16x32_bf16(bk1[tc], aq[g][1], sacc[tc], 0, 0, 0);
                }
                if (kt * 64 + 63 > gb) {             // diagonal tile: mask
                    int qrow = gb + lcol;
                    #pragma unroll
                    for (int tc = 0; tc < 4; ++tc) {
                        float p[4];
                        #pragma unroll
                        for (int r = 0; r < 4; ++r) {
                            float e = __builtin_amdgcn_exp2f(sacc[tc][r] * SC);
                            p[r] = (kt * 64 + tc * 16 + quad * 4 + r > qrow) ? 0.f : e;
                        }
                        pk[g][tc] = pack4bf(p[0], p[1], p[2], p[3]);
                    }
                } else {
                    #pragma unroll
                    for (int tc = 0; tc < 4; ++tc) {
                        pk[g][tc] = pack4bf(
                            __builtin_amdgcn_exp2f(sacc[tc][0] * SC),
                            __builtin_amdgcn_exp2f(sacc[tc][1] * SC),
                            __builtin_amdgcn_exp2f(sacc[tc][2] * SC),
                            __builtin_amdgcn_exp2f(sacc[tc][3] * SC));
                    }
                }
            }
        }

        // O^T += V^T * P^T  -- V frags read ONCE per wave, both groups
        if (act[0]) {
            #pragma unroll
            for (int td = 0; td < 4; ++td) {
                short4v va[4];
                #pragma unroll
                for (int tc = 0; tc < 4; ++tc) {
                    int seg = ((tc << 1) + (quad >> 1)) ^ (lcol & 7);
                    va[tc] = *(const short4v*)(vsr + ((td * 16 + lcol) << 6) + (seg << 3) + ((quad & 1) << 2));
                }
                #pragma unroll
                for (int tc = 0; tc < 4; ++tc)
                    O[0][td] = MFMA16K16(va[tc], pk[0][tc], O[0][td]);
                if (act[1]) {
                    #pragma unroll
                    for (int tc = 0; tc < 4; ++tc)
                        O[1][td] = MFMA16K16(va[tc], pk[1][tc], O[1][td]);
                }
            }
        } else if (act[1]) {
            #pragma unroll
            for (int td = 0; td < 4; ++td) {
                short4v va[4];
                #pragma unroll
                for (int tc = 0; tc < 4; ++tc) {
                    int seg = ((tc << 1) + (quad >> 1)) ^ (lcol & 7);
                    va[tc] = *(const short4v*)(vsr + ((td * 16 + lcol) << 6) + (seg << 3) + ((quad & 1) << 2));
                }
                #pragma unroll
                for (int tc = 0; tc < 4; ++tc)
                    O[1][td] = MFMA16K16(va[tc], pk[1][tc], O[1][td]);
            }
        }
        // l[q] += sum_key P^T[key][q]
        #pragma unroll
        for (int g = 0; g < 2; ++g) {
            if (act[g]) {
                #pragma unroll
                for (int tc = 0; tc < 4; ++tc)
                    lacc[g] = MFMA16K16(ones4, pk[g][tc], lacc[g]);
            }
        }

        __builtin_amdgcn_sched_barrier(0);
        if (kt + 2 < t1) STAGE(kt + 2, (kt + 2) % 3);   // buf (kt+2)%3 == (kt-1)%3: readers done
    }
#undef STAGE

    if (nc == 1) {
        // ---- single chunk (qt3 0,1): final normalize + write ----
        int b = bh >> 4, h = bh & 15;
        #pragma unroll
        for (int g = 0; g < 2; ++g) {
            int qrow = q0 + g * 128 + 16 * w + lcol;
            float inv = 1.0f / lacc[g][0];
            size_t obase = ((size_t)b * SEQ + qrow) * EMB + (size_t)h * HD + quad * 4;
            #pragma unroll
            for (int td = 0; td < 4; ++td) {
                short4v ov;
                #pragma unroll
                for (int r = 0; r < 4; ++r) ov[r] = (short)f2bf(O[g][td][r] * inv);
                *(short4v*)(&Out[obase + td * 16]) = ov;
            }
        }
    } else if (ci == 0) {
        // ---- chunk 0: RAW bf16 O into final Out rows; l into Laux ----
        int b = bh >> 4, h = bh & 15;
        float* lrow = Laux + ((size_t)bh * 6 + (qt3 - 2)) * 256;
        #pragma unroll
        for (int g = 0; g < 2; ++g) {
            int ql = g * 128 + 16 * w + lcol;
            int qrow = q0 + ql;
            size_t obase = ((size_t)b * SEQ + qrow) * EMB + (size_t)h * HD + quad * 4;
            #pragma unroll
            for (int td = 0; td < 4; ++td) {
                short4v ov;
                #pragma unroll
                for (int r = 0; r < 4; ++r) ov[r] = (short)f2bf(O[g][td][r]);
                *(short4v*)(&Out[obase + td * 16]) = ov;
            }
            if (quad == 0) lrow[ql] = lacc[g][0];
        }
    } else {
        // ---- chunks ci>=1: partial slot (raw bf16 O + f32 l) ----
        unsigned char* sp = Part
            + (size_t)(bh * SLOTS_PER_BH + slot_off(qt3, ci)) * SLOT_B;
        unsigned short* sO = (unsigned short*)sp;       // [q_local 0..255][d 0..63]
        float* sL = (float*)(sp + 32768);
        #pragma unroll
        for (int g = 0; g < 2; ++g) {
            int ql = g * 128 + 16 * w + lcol;
            #pragma unroll
            for (int td = 0; td < 4; ++td) {
                short4v ov;
                #pragma unroll
                for (int r = 0; r < 4; ++r) ov[r] = (short)f2bf(O[g][td][r]);
                *(short4v*)(&sO[ql * 64 + td * 16 + quad * 4]) = ov;
            }
            if (quad == 0) sL[ql] = lacc[g][0];
        }
    }
}

// merge chunk-0 (raw in Out + Laux) with slots 1..nc-1, normalize, rewrite Out
__global__ __launch_bounds__(256) void attn_combine(
    const unsigned char* __restrict__ Part, const float* __restrict__ Laux,
    unsigned short* __restrict__ Out)
{
    int qt3 = 2 + (int)blockIdx.x;           // 2..7
    int bh = blockIdx.y;
    int nc = (qt3 + 2) >> 1;                 // 2..4
    const unsigned char* base = Part
        + (size_t)(bh * SLOTS_PER_BH + slot_off(qt3, 1)) * SLOT_B;
    const float* lrow = Laux + ((size_t)bh * 6 + (qt3 - 2)) * 256;
    int b = bh >> 4, h = bh & 15;
    size_t obase = ((size_t)b * SEQ + qt3 * 256) * EMB + (size_t)h * HD;
    int t = threadIdx.x;
    #pragma unroll
    for (int it = 0; it < 8; ++it) {
        int job = it * 256 + t;              // 0..2047 = 256 rows x 8 col-chunks
        int row = job >> 3, c8 = (job & 7) * 8;
        unsigned short* op = &Out[obase + (size_t)row * EMB + c8];
        float acc8[8];
        short8 v0 = *(const short8*)op;      // chunk-0 raw partial
        #pragma unroll
        for (int e = 0; e < 8; ++e) acc8[e] = bf2f((unsigned short)v0[e]);
        float lsum = lrow[row];
        for (int k = 1; k < nc; ++k) {
            const unsigned char* sp = base + (size_t)(k - 1) * SLOT_B;
            const unsigned short* sO = (const unsigned short*)sp;
            const float* sL = (const float*)(sp + 32768);
            short8 vv = *(const short8*)(&sO[row * 64 + c8]);
            #pragma unroll
            for (int e = 0; e < 8; ++e) acc8[e] += bf2f((unsigned short)vv[e]);
            lsum += sL[row];
        }
        float inv = 1.0f / lsum;
        short8 ov;
        #pragma unroll
        for (int e = 0; e < 8; ++e) ov[e] = (short)f2bf(acc8[e] * inv);
        *(short8*)op = ov;
    }
}

// ---------------------------------------------------------------------------
// Output projection: counted-vmcnt 3-buffer pipeline, EXACT mirror of the
// attn loop ordering (vmcnt@top -> barrier -> sched_barrier -> compute ->
// sched_barrier -> STAGE(it+2) at end). fp32 bias, fp32 out.
// ---------------------------------------------------------------------------
__global__ __launch_bounds__(256) void oproj_gemm(
    const unsigned short* __restrict__ A,    // [4096][1024] bf16
    const unsigned short* __restrict__ Bt,   // W_o^T [1024][1024] bf16
    const float* __restrict__ bias,          // [1024] fp32
    float* __restrict__ Cout)                // [4096][1024] fp32
{
    const int K = EMB;
    __shared__ __align__(16) unsigned short smem[3 * 8192];   // 48KB, 3 buffers
    int t = threadIdx.x;
    int m0 = blockIdx.y * 128;
    int n0 = blockIdx.x * 128;
    int w = t >> 6, lane = t & 63, quad = lane >> 4, lcol = lane & 15;
    int wr = w >> 1, wc = w & 1;

    floatx4 zero = {0.f, 0.f, 0.f, 0.f};
    floatx4 acc[4][4];
    #pragma unroll
    for (int i = 0; i < 4; ++i)
        #pragma unroll
        for (int j = 0; j < 4; ++j) acc[i][j] = zero;

    const unsigned short* a0 = A  + (size_t)(m0 + (t >> 2)) * K + ((t & 3) << 3);
    const unsigned short* b0 = Bt + (size_t)(n0 + (t >> 2)) * K + ((t & 3) << 3);
    unsigned short* la = &smem[t << 3];

#define OSTAGE(k0_, b_) do { \
        GLL(a0 + (k0_), la + (b_) * 8192); \
        GLL(a0 + 64 * K + (k0_), la + (b_) * 8192 + 2048); \
        GLL(b0 + (k0_), la + (b_) * 8192 + 4096); \
        GLL(b0 + 64 * K + (k0_), la + (b_) * 8192 + 6144); \
    } while (0)

    // prologue: depth-2 prefetch (tiles 0 and 1)
    OSTAGE(0, 0);
    OSTAGE(32, 1);

    for (int k0 = 0; k0 < K; k0 += 32) {
        int it = k0 >> 5;
        // FIFO: outstanding = {it:4, it+1:4}; vmcnt(4) retires exactly tile it
        if (k0 + 32 < K) asm volatile("s_waitcnt vmcnt(4)" ::: "memory");
        else             asm volatile("s_waitcnt vmcnt(0)" ::: "memory");
        __builtin_amdgcn_s_barrier();
        __builtin_amdgcn_sched_barrier(0);

        const unsigned short* As = &smem[(it % 3) * 8192];
        const unsigned short* Bs = As + 4096;
        short8 af[4], bfm[4];
        #pragma unroll
        for (int i = 0; i < 4; ++i)
            af[i] = *(const short8*)(&As[(wr * 64 + i * 16 + lcol) * 32 + quad * 8]);
        #pragma unroll
        for (int j = 0; j < 4; ++j)
            bfm[j] = *(const short8*)(&Bs[(wc * 64 + j * 16 + lcol) * 32 + quad * 8]);
        #pragma unroll
        for (int i = 0; i < 4; ++i)
            #pragma unroll
            for (int j = 0; j < 4; ++j)
                acc[i][j] = __builtin_amdgcn_mfma_f32_16x16x32_bf16(af[i], bfm[j], acc[i][j], 0, 0, 0);

        __builtin_amdgcn_sched_barrier(0);
        // stage tile it+2 into buf (it+2)%3 == (it-1)%3: its readers (iter
        // it-1) all crossed the iter-it barrier above.
        if (k0 + 64 < K) OSTAGE(k0 + 64, (it + 2) % 3);
    }
#undef OSTAGE

    #pragma unroll
    for (int i = 0; i < 4; ++i) {
        int m = m0 + wr * 64 + i * 16 + quad * 4;
        #pragma unroll
        for (int j = 0; j < 4; ++j) {
            int n = n0 + wc * 64 + j * 16 + lcol;
            float bv = bias[n];
            #pragma unroll
            for (int r = 0; r < 4; ++r)
                Cout[(size_t)(m + r) * EMB + n] = acc[i][j][r] + bv;
        }
    }
}

// ---------------------------------------------------------------------------
extern "C" void kernel_launch(void* const* d_in, const int* in_sizes, int n_in,
                              void* d_out, int out_size, void* d_ws, size_t ws_size,
                              hipStream_t stream) {
    (void)in_sizes; (void)n_in; (void)out_size; (void)ws_size;
    char* ws = (char*)d_ws;
    const size_t OFF_X     = 0;                                      // 8 MB
    const size_t OFF_WQKVT = OFF_X     + (size_t)M_ROWS * EMB * 2;   // 6 MB
    const size_t OFF_WOT   = OFF_WQKVT + (size_t)N_QKV * EMB * 2;    // 2 MB
    const size_t OFF_Q     = OFF_WOT   + (size_t)EMB * EMB * 2;      // 8 MB
    const size_t OFF_K     = OFF_Q     + (size_t)M_ROWS * EMB * 2;   // 8 MB
    const size_t OFF_V     = OFF_K     + (size_t)M_ROWS * EMB * 2;   // 8 MB
    const size_t OFF_ATTN  = OFF_V     + (size_t)M_ROWS * EMB * 2;   // 8 MB
    // Partials OVERLAY x_bf+wqkvT (dead after qkv_gemm). 12.97MB + 0.19MB
    // fits in the 14MB region; woT at +14MB untouched. Total ws use: 48MB.
    const size_t OFF_PART  = OFF_X;
    const size_t OFF_LAUX  = OFF_PART + (size_t)32 * SLOTS_PER_BH * SLOT_B;

    const float* x    = (const float*)d_in[0];
    const float* Wqkv = (const float*)d_in[1];
    const float* bqkv = (const float*)d_in[2];
    const float* Wo   = (const float*)d_in[3];
    const float* bo   = (const float*)d_in[4];

    unsigned short* x_bf  = (unsigned short*)(ws + OFF_X);
    unsigned short* wqkvT = (unsigned short*)(ws + OFF_WQKVT);
    unsigned short* woT   = (unsigned short*)(ws + OFF_WOT);
    unsigned short* qb    = (unsigned short*)(ws + OFF_Q);
    unsigned short* kb    = (unsigned short*)(ws + OFF_K);
    unsigned short* vb    = (unsigned short*)(ws + OFF_V);    // [B,H,D,S]
    unsigned short* attn  = (unsigned short*)(ws + OFF_ATTN);
    unsigned char*  part  = (unsigned char*)(ws + OFF_PART);
    float*          laux  = (float*)(ws + OFF_LAUX);

    prep<<<dim3(96, 32, 3), dim3(32, 8), 0, stream>>>(x, Wqkv, Wo, x_bf, wqkvT, woT);

    qkv_gemm<<<dim3(N_QKV / 128, M_ROWS / 128), 256, 0, stream>>>(x_bf, wqkvT, bqkv, qb, kb, vb);
    attn_fused<<<dim3(20, NB * NH), 512, 0, stream>>>(qb, kb, vb, attn, part, laux);
    attn_combine<<<dim3(6, NB * NH), 256, 0, stream>>>(part, laux, attn);
    oproj_gemm<<<dim3(EMB / 128, M_ROWS / 128), 256, 0, stream>>>(attn, woT, bo, (float*)d_out);
}